// Round 15
// baseline (2782.288 us; speedup 1.0000x reference)
//
#include <hip/hip_runtime.h>
#include <math.h>

// ---------------------------------------------------------------------------
// RSSM: B=16, T=64 (bt=1024), encoder 3->32->64->128->256 (k4 s2 p1) with
// full-tensor LayerNorm+SiLU per layer, fc 4096->256, GRU(1030->128),
// prior 128->1024, post 384->1024, z = per-32-chunk argmax one-hot.
// All fp32: one flipped argmax = 1.0 error in z -> low precision in the
// logit path is fatal.
// R18 changes (from profile): conv3_r 461us with 35.1M LDS bank conflicts
// -- the R6 LDS weight path itself: 128 staging b128 writes/wave at
// ~16-way conflict + 4096 broadcast b128 weight reads/wave saturate the
// LDS pipe (~400K cy/CU vs 109us VALU floor). Fix: weights OUT of LDS --
// 4 waves x 32 oc, 1 position/lane (64 pos = 64 lanes), acc[32]; weight
// pointer readfirstlane-scalarized -> s_load (scalar fmac operand, conv1's
// pattern). Input staged in 16-ch chunks, row-stride 17 (banks ~4-way for
// any tap), scalar writes. LDS 37->17.7KB, barriers 32->8, weight LDS
// machinery deleted.
// ---------------------------------------------------------------------------

__device__ __forceinline__ float silu_f(float t){ return t / (1.f + __expf(-t)); }
__device__ __forceinline__ float sigm_f(float x){ return 1.f / (1.f + expf(-x)); }

// Block-level mean/rstd over m values; each thread contributes (s, s2).
__device__ __forceinline__ void block_stats_256(float s, float s2, int m,
                                                float& mean, float& rstd)
{
    __shared__ float red[8];
#pragma unroll
    for (int off = 32; off > 0; off >>= 1) {
        s  += __shfl_down(s, off);
        s2 += __shfl_down(s2, off);
    }
    int wv = threadIdx.x >> 6;
    if ((threadIdx.x & 63) == 0) { red[wv] = s; red[4 + wv] = s2; }
    __syncthreads();
    if (threadIdx.x == 0) {
        float S  = (red[0] + red[1]) + (red[2] + red[3]);
        float S2 = (red[4] + red[5]) + (red[6] + red[7]);
        float mu = S / m;
        float var = S2 / m - mu * mu;
        red[0] = mu;
        red[1] = rsqrtf(var + 1e-5f);
    }
    __syncthreads();
    mean = red[0]; rstd = red[1];
}

// ---------------- fused LayerNorm+SiLU, one block per sample ---------------
__global__ __launch_bounds__(256) void ln_fuse_k(float* __restrict__ x,
    const float* __restrict__ g, const float* __restrict__ b, int m)
{
    int n = blockIdx.x;
    float* p = x + (size_t)n * m;
    float s = 0.f, s2 = 0.f;
    for (int i = threadIdx.x * 4; i < m; i += 1024) {
        float4 v = *(const float4*)(p + i);
        s  += (v.x + v.y) + (v.z + v.w);
        s2 += (v.x*v.x + v.y*v.y) + (v.z*v.z + v.w*v.w);
    }
    float mean, rstd;
    block_stats_256(s, s2, m, mean, rstd);
    for (int i = threadIdx.x * 4; i < m; i += 1024) {
        float4 v  = *(float4*)(p + i);
        float4 gv = *(const float4*)(g + i);
        float4 bv = *(const float4*)(b + i);
        v.x = silu_f((v.x - mean) * rstd * gv.x + bv.x);
        v.y = silu_f((v.y - mean) * rstd * gv.y + bv.y);
        v.z = silu_f((v.z - mean) * rstd * gv.z + bv.z);
        v.w = silu_f((v.w - mean) * rstd * gv.w + bv.w);
        *(float4*)(p + i) = v;
    }
}

// ------------------------- conv1: 3x64x64 -> 32x32x32 ----------------------
__global__ __launch_bounds__(256) void conv1_k(const float* __restrict__ in,
    const float* __restrict__ w, const float* __restrict__ bias, float* __restrict__ out)
{
    int n  = blockIdx.x;                 // chunk-local sample
    int yq = blockIdx.y;                 // 4 y-quarters
    int tx = threadIdx.x & 31;
    int ty = threadIdx.x >> 5;           // 0..7
    int y  = yq * 8 + ty;                // 0..31
    const float* ip = in + (size_t)n * 12288;

    float okf[16]; int offs[16];
#pragma unroll
    for (int ky = 0; ky < 4; ky++) {
        int yy = 2 * y - 1 + ky;
        bool yok = ((unsigned)yy < 64u);
#pragma unroll
        for (int kx = 0; kx < 4; kx++) {
            int xx = 2 * tx - 1 + kx;
            bool ok = yok && ((unsigned)xx < 64u);
            okf[ky*4+kx]  = ok ? 1.f : 0.f;
            offs[ky*4+kx] = ok ? yy * 64 + xx : 0;
        }
    }
    float iv[48];
#pragma unroll
    for (int c = 0; c < 3; c++)
#pragma unroll
        for (int q = 0; q < 16; q++)
            iv[c*16+q] = ip[c*4096 + offs[q]] * okf[q];

    float* op = out + (size_t)n * 32768 + y * 32 + tx;
#pragma unroll 4
    for (int oc = 0; oc < 32; oc++) {           // oc uniform -> weights s_load
        float acc = bias[oc];
        const float* wp = w + oc * 48;
#pragma unroll
        for (int q = 0; q < 48; q++) acc += iv[q] * wp[q];
        op[oc * 1024] = acc;
    }
}

// ------- conv2 + LN2 + SiLU: 32x32x32 -> 64x16x16 -------------------------
__global__ __launch_bounds__(256) void conv2_r(const float* __restrict__ in,
    const float* __restrict__ w, const float* __restrict__ bias,
    const float* __restrict__ lg, const float* __restrict__ lb,
    float* __restrict__ out)
{
    __shared__ __align__(16) float lds[8208];     // 4*1028 input + 4096 wt
    int n  = blockIdx.x;
    int tid = threadIdx.x;
    int wv  = tid >> 6;
    int g   = wv >> 1;                            // oc half 0/1
    int s   = ((wv & 1) << 6) | (tid & 63);       // 0..127
    int x   = s & 15, y0 = s >> 4;                // x 0..15, y0 0..7
    const float* ip = in + (size_t)n * 32768;

    int offs[2][16];
#pragma unroll
    for (int p = 0; p < 2; p++) {
        int y = y0 + 8 * p;
#pragma unroll
        for (int ky = 0; ky < 4; ky++) {
            int yi = 2 * y - 1 + ky;
#pragma unroll
            for (int kx = 0; kx < 4; kx++) {
                int xi = 2 * x - 1 + kx;
                bool ok = ((unsigned)yi < 32u) && ((unsigned)xi < 32u);
                int rot = ((xi >> 2) + (yi & 7)) & 7;
                int foff = yi * 32 + rot * 4 + (xi & 3);
                offs[p][ky*4+kx] = ok ? (4 + foff) * 4 : 0;   // bytes; 0 = zero slot
            }
        }
    }
    if (tid < 16) lds[(tid >> 2) * 1028 + (tid & 3)] = 0.f;   // zero slots

    float acc0[32], acc1[32];
#pragma unroll
    for (int i = 0; i < 32; i++) { float bv = bias[g*32 + i]; acc0[i] = bv; acc1[i] = bv; }

#pragma unroll 1
    for (int ch = 0; ch < 8; ch++) {              // 8 chunks x 4 channels
        __syncthreads();
        {   // stage input: 4 ch x 1024 fl, rotated rows
            const float4* gs = (const float4*)(ip + (ch << 12));
#pragma unroll
            for (int k = 0; k < 4; k++) {
                int gid = tid + (k << 8);         // 0..1023 f4s
                int cc = gid >> 8, r = (gid >> 3) & 31, s4 = gid & 7;
                int rs = (s4 + (r & 7)) & 7;
                *(float4*)&lds[cc*1028 + 4 + r*32 + rs*4] = gs[gid];
            }
            // stage weights: 4 ch x 64 oc x 16
            int oc = tid >> 2, i4 = tid & 3;
            const float* wg = w + (size_t)oc * 512 + (ch << 6) + i4 * 4;
#pragma unroll
            for (int cc = 0; cc < 4; cc++)
                *(float4*)&lds[4112 + cc*1024 + oc*16 + i4*4] =
                    *(const float4*)(wg + cc * 16);
        }
        __syncthreads();
#pragma unroll 1
        for (int cc = 0; cc < 4; cc++) {
            const char* cb = (const char*)lds + cc * 4112;
            float iv0[16], iv1[16];
#pragma unroll
            for (int q = 0; q < 16; q++) {
                iv0[q] = *(const float*)(cb + offs[0][q]);
                iv1[q] = *(const float*)(cb + offs[1][q]);
            }
            const float* wb = &lds[4112 + cc*1024 + g*512];   // wave-uniform base
#pragma unroll
            for (int o = 0; o < 32; o++) {
                float wt[16];
                *(float4*)&wt[0]  = *(const float4*)(wb + o*16);
                *(float4*)&wt[4]  = *(const float4*)(wb + o*16 + 4);
                *(float4*)&wt[8]  = *(const float4*)(wb + o*16 + 8);
                *(float4*)&wt[12] = *(const float4*)(wb + o*16 + 12);
#pragma unroll
                for (int q = 0; q < 16; q++) {
                    acc0[o] = fmaf(iv0[q], wt[q], acc0[o]);
                    acc1[o] = fmaf(iv1[q], wt[q], acc1[o]);
                }
            }
        }
    }
    // ---- fused LN2 + SiLU over the block-resident 16384 values ----
    float s1 = 0.f, s2 = 0.f;
#pragma unroll
    for (int o = 0; o < 32; o++) {
        s1 += acc0[o] + acc1[o];
        s2 += acc0[o]*acc0[o] + acc1[o]*acc1[o];
    }
    float mean, rstd;
    block_stats_256(s1, s2, 16384, mean, rstd);

    float* op = out + (size_t)n * 16384;
#pragma unroll
    for (int o = 0; o < 32; o++) {
        int f0 = (g*32 + o) * 256 + y0*16 + x;
        int f1 = (g*32 + o) * 256 + (y0+8)*16 + x;
        op[f0] = silu_f((acc0[o] - mean) * rstd * lg[f0] + lb[f0]);
        op[f1] = silu_f((acc1[o] - mean) * rstd * lg[f1] + lb[f1]);
    }
}

// ------- conv3 + LN3 + SiLU: 64x16x16 -> 128x8x8 ---------------------------
// R18: 4 waves x 32 oc, 1 position/lane (64 pos). Weights via wave-uniform
// s_load (no LDS). Input staged in 16-ch chunks, row stride 17 -> ~4-way
// max bank aliasing on any tap. acc[32] static; LN3 fused (m=8192).
__global__ __launch_bounds__(256) void conv3_r(const float* __restrict__ in,
    const float* __restrict__ w, const float* __restrict__ bias,
    const float* __restrict__ lg, const float* __restrict__ lb,
    float* __restrict__ out)
{
    __shared__ float lds[4416];          // 16 ch x (4 zero + 16 rows x 17)
    int n   = blockIdx.x;
    int tid = threadIdx.x;
    int ocb = __builtin_amdgcn_readfirstlane((tid >> 6) << 5);  // wave id * 32
    int s0  = tid & 63, y = s0 >> 3, x = s0 & 7;

    int offs[16];
#pragma unroll
    for (int ky = 0; ky < 4; ky++) {
        int yi = 2 * y - 1 + ky;
#pragma unroll
        for (int kx = 0; kx < 4; kx++) {
            int xi = 2 * x - 1 + kx;
            bool ok = ((unsigned)yi < 16u) && ((unsigned)xi < 16u);
            offs[ky*4+kx] = ok ? (4 + yi * 17 + xi) : (tid & 3);  // 0..3 zero slot
        }
    }
    if (tid < 64) lds[(tid >> 2) * 276 + (tid & 3)] = 0.f;        // zero slots

    float acc[32];
#pragma unroll
    for (int i = 0; i < 32; i++) acc[i] = bias[ocb + i];

    const float* ip = in + (size_t)n * 16384;
#pragma unroll 1
    for (int ch = 0; ch < 4; ch++) {              // 4 chunks x 16 channels
        __syncthreads();
        {   // stage 16 ch x 256 fl (scalar writes into stride-17 rows)
            const float4* gs = (const float4*)(ip + (ch << 12));
#pragma unroll
            for (int k = 0; k < 4; k++) {
                int gid = tid + (k << 8);         // 0..1023 f4s
                int cc = gid >> 6, j = gid & 63;
                int r = j >> 2, s4 = j & 3;
                float4 v = gs[gid];
                float* d = &lds[cc*276 + 4 + r*17 + s4*4];
                d[0] = v.x; d[1] = v.y; d[2] = v.z; d[3] = v.w;
            }
        }
        __syncthreads();
#pragma unroll 1
        for (int cl = 0; cl < 16; cl++) {
            int c = (ch << 4) + cl;
            const float* cb = &lds[cl * 276];
            float iv[16];
#pragma unroll
            for (int q = 0; q < 16; q++) iv[q] = cb[offs[q]];
            const float* wp = w + ((size_t)ocb * 64 + c) * 16;   // wave-uniform
#pragma unroll
            for (int o = 0; o < 32; o++) {
                const float* wo = wp + o * 1024;                 // s_load x16
#pragma unroll
                for (int q = 0; q < 16; q++)
                    acc[o] = fmaf(iv[q], wo[q], acc[o]);
            }
        }
    }
    // ---- fused LN3 + SiLU over the block-resident 8192 values ----
    float s1 = 0.f, s2 = 0.f;
#pragma unroll
    for (int o = 0; o < 32; o++) { s1 += acc[o]; s2 += acc[o]*acc[o]; }
    float mean, rstd;
    block_stats_256(s1, s2, 8192, mean, rstd);

    float* op = out + (size_t)n * 8192;
#pragma unroll
    for (int o = 0; o < 32; o++) {
        int f0 = (ocb + o) * 64 + s0;
        op[f0] = silu_f((acc[o] - mean) * rstd * lg[f0] + lb[f0]);
    }
}

// ----- c4wT[c][oc][q] = conv4_w[oc][c*16+q]  (coalesced per-channel rows) --
__global__ __launch_bounds__(256) void tr_c4_k(const float* __restrict__ w,
                                               float* __restrict__ wt)
{
    int gi = blockIdx.x * 256 + threadIdx.x;     // 0..524287
    int q  = gi & 15;
    int t  = gi >> 4;                            // c*256 + oc
    int oc = t & 255;
    int c  = t >> 8;
    wt[gi] = w[(size_t)oc * 2048 + c * 16 + q];
}

// ----------------- conv4 + LN4 + SiLU: 128x8x8 -> 256x4x4 ------------------
__global__ __launch_bounds__(256) void conv4_f(const float* __restrict__ in,
    const float* __restrict__ wT, const float* __restrict__ bias,
    const float* __restrict__ g, const float* __restrict__ bet, float* __restrict__ out)
{
    int n  = blockIdx.x;
    int oc = threadIdx.x;                 // 0..255
    const float* ip = in + (size_t)n * 8192;

    float acc[16];
#pragma unroll
    for (int s = 0; s < 16; s++) acc[s] = bias[oc];

#pragma unroll 2
    for (int c = 0; c < 128; c++) {
        const float* ic = ip + c * 64;     // uniform base -> s_load, CSE'd
        const float4* wp = (const float4*)(wT + ((size_t)c * 256 + oc) * 16);
        float wf[16];
        *(float4*)&wf[0]  = wp[0];         // coalesced: lane stride 64B
        *(float4*)&wf[4]  = wp[1];
        *(float4*)&wf[8]  = wp[2];
        *(float4*)&wf[12] = wp[3];
#pragma unroll
        for (int y = 0; y < 4; y++)
#pragma unroll
        for (int x = 0; x < 4; x++) {
            float a = acc[y * 4 + x];
#pragma unroll
            for (int ky = 0; ky < 4; ky++) {
                int yy = 2 * y - 1 + ky;
                if (yy < 0 || yy > 7) continue;      // folds at compile time
#pragma unroll
                for (int kx = 0; kx < 4; kx++) {
                    int xx = 2 * x - 1 + kx;
                    if (xx < 0 || xx > 7) continue;
                    a += wf[ky * 4 + kx] * ic[yy * 8 + xx];
                }
            }
            acc[y * 4 + x] = a;
        }
    }
    float s = 0.f, s2 = 0.f;
#pragma unroll
    for (int q = 0; q < 16; q++) { s += acc[q]; s2 += acc[q] * acc[q]; }
    float mean, rstd;
    block_stats_256(s, s2, 4096, mean, rstd);

    float* op = out + (size_t)n * 4096;
#pragma unroll
    for (int q = 0; q < 16; q++) {
        int flat = oc * 16 + q;
        float v = (acc[q] - mean) * rstd * g[flat] + bet[flat];
        op[flat] = silu_f(v);
    }
}

// -------- transpose fc_w [256][4096] -> fcwT [4096][256] (LDS-tiled) -------
__global__ __launch_bounds__(256) void trfc_k(const float* __restrict__ w,
                                              float* __restrict__ wt)
{
    __shared__ float t[32][33];
    int bk = blockIdx.x * 32;             // k dim (4096)
    int bj = blockIdx.y * 32;             // j dim (256)
    int lx = threadIdx.x & 31, ly = threadIdx.x >> 5;   // 32 x 8
#pragma unroll
    for (int s = 0; s < 4; s++)
        t[ly + 8*s][lx] = w[(size_t)(bj + ly + 8*s) * 4096 + bk + lx];
    __syncthreads();
#pragma unroll
    for (int s = 0; s < 4; s++)
        wt[(size_t)(bk + ly + 8*s) * 256 + bj + lx] = t[lx][ly + 8*s];
}

// ---------------- fc: [S,4096] @ wT[4096][256], coalesced ------------------
__global__ __launch_bounds__(256) void fc_k2(const float* __restrict__ a,
    const float* __restrict__ wT, const float* __restrict__ bias, float* __restrict__ o)
{
    int n0 = blockIdx.x * 8;              // chunk-local rows
    int j  = threadIdx.x;
    float acc[8];
#pragma unroll
    for (int r = 0; r < 8; r++) acc[r] = 0.f;
    for (int k = 0; k < 4096; k += 4) {
        float wv0 = wT[(size_t)k * 256 + j];
        float wv1 = wT[(size_t)(k+1) * 256 + j];
        float wv2 = wT[(size_t)(k+2) * 256 + j];
        float wv3 = wT[(size_t)(k+3) * 256 + j];
#pragma unroll
        for (int r = 0; r < 8; r++) {
            const float* ar = a + (size_t)(n0 + r) * 4096 + k;   // uniform -> s_load x4
            acc[r] += wv0*ar[0] + wv1*ar[1] + wv2*ar[2] + wv3*ar[3];
        }
    }
    float bj = bias[j];
#pragma unroll
    for (int r = 0; r < 8; r++) o[(size_t)(n0 + r) * 256 + j] = acc[r] + bj;
}

// ----------- Fpost[n,j] = post_b[j] + feats[n,:] @ post_w[j,128:384] -------
__global__ __launch_bounds__(256) void fpost_k(const float* __restrict__ f,
    const float* __restrict__ w, const float* __restrict__ bias, float* __restrict__ o)
{
    int n0 = blockIdx.x * 4;
    int tid = threadIdx.x;
    float acc[4][4];
#pragma unroll
    for (int r = 0; r < 4; r++)
#pragma unroll
        for (int jj = 0; jj < 4; jj++) acc[r][jj] = 0.f;
    for (int k = 0; k < 256; k += 4) {
        float4 wv[4];
#pragma unroll
        for (int jj = 0; jj < 4; jj++)
            wv[jj] = *(const float4*)(w + (size_t)(tid + jj * 256) * 384 + 128 + k);
#pragma unroll
        for (int r = 0; r < 4; r++) {
            const float* fr = f + (size_t)(n0 + r) * 256 + k;    // uniform
            float a0 = fr[0], a1 = fr[1], a2 = fr[2], a3 = fr[3];
#pragma unroll
            for (int jj = 0; jj < 4; jj++)
                acc[r][jj] += wv[jj].x*a0 + wv[jj].y*a1 + wv[jj].z*a2 + wv[jj].w*a3;
        }
    }
#pragma unroll
    for (int jj = 0; jj < 4; jj++) {
        float bj = bias[tid + jj * 256];
#pragma unroll
        for (int r = 0; r < 4; r++)
            o[(size_t)(n0 + r) * 1024 + tid + jj * 256] = acc[r][jj] + bj;
    }
}

// ----------- prior[n,j] = prior_b[j] + h[n,:] @ prior_w[j,:] ---------------
__global__ __launch_bounds__(256) void prior_k(const float* __restrict__ h,
    const float* __restrict__ w, const float* __restrict__ bias, float* __restrict__ o)
{
    int n0 = blockIdx.x * 4;
    int tid = threadIdx.x;
    float acc[4][4];
#pragma unroll
    for (int r = 0; r < 4; r++)
#pragma unroll
        for (int jj = 0; jj < 4; jj++) acc[r][jj] = 0.f;
    for (int k = 0; k < 128; k += 4) {
        float4 wv[4];
#pragma unroll
        for (int jj = 0; jj < 4; jj++)
            wv[jj] = *(const float4*)(w + (size_t)(tid + jj * 256) * 128 + k);
#pragma unroll
        for (int r = 0; r < 4; r++) {
            const float* hr = h + (size_t)(n0 + r) * 128 + k;    // uniform
            float a0 = hr[0], a1 = hr[1], a2 = hr[2], a3 = hr[3];
#pragma unroll
            for (int jj = 0; jj < 4; jj++)
                acc[r][jj] += wv[jj].x*a0 + wv[jj].y*a1 + wv[jj].z*a2 + wv[jj].w*a3;
        }
    }
#pragma unroll
    for (int jj = 0; jj < 4; jj++) {
        float bj = bias[tid + jj * 256];
#pragma unroll
        for (int r = 0; r < 4; r++)
            o[(size_t)(n0 + r) * 1024 + tid + jj * 256] = acc[r][jj] + bj;
    }
}

// ----------- Ai[n,j] = bih[j] + actions[n,:] @ wih[j,1024:1030] ------------
__global__ __launch_bounds__(128) void ai_k(const float* __restrict__ act,
    const float* __restrict__ wih, const float* __restrict__ bih, float* __restrict__ o)
{
    int n = blockIdx.x;
    int j = blockIdx.y * 128 + threadIdx.x;     // 0..383
    const float* ar = act + (size_t)n * 6;       // uniform
    const float* wr = wih + (size_t)j * 1030 + 1024;
    float acc = bih[j];
#pragma unroll
    for (int k = 0; k < 6; k++) acc += ar[k] * wr[k];
    o[(size_t)n * 384 + j] = acc;
}

// ----------- wihT[k,j] = wih[j,k]  (z-part only, k<1024) -------------------
__global__ __launch_bounds__(256) void tr_k(const float* __restrict__ wih,
                                            float* __restrict__ wt)
{
    int g = blockIdx.x * 256 + threadIdx.x;      // 0..393215
    int k = g / 384;
    int j = g - k * 384;
    wt[g] = wih[(size_t)j * 1030 + k];
}

// ----- whhV[k4][j][c] = whh[j][4*k4+c]  (float4-packed, coalesced) ---------
__global__ __launch_bounds__(256) void tr_whh_k(const float* __restrict__ whh,
                                                float* __restrict__ wt)
{
    int g = blockIdx.x * 256 + threadIdx.x;      // 0..49151
    int c  = g & 3;
    int jk = g >> 2;                             // 0..12287
    int j  = jk % 384;
    int k4 = jk / 384;                           // 0..31
    wt[g] = whh[(size_t)j * 128 + k4 * 4 + c];
}

// ----- pwV[k4][j][c] = post_w[j][4*k4+c] (h-cols only, float4-packed) ------
__global__ __launch_bounds__(256) void tr_pw_k(const float* __restrict__ pw,
                                               float* __restrict__ wt)
{
    int g = blockIdx.x * 256 + threadIdx.x;      // 0..131071
    int c  = g & 3;
    int jk = g >> 2;                             // 0..32767
    int j  = jk & 1023;
    int k4 = jk >> 10;                           // 0..31
    wt[g] = pw[(size_t)j * 384 + k4 * 4 + c];
}

// ------------------- GRU recurrence (1 block / sample, 32 steps) -----------
__global__ __launch_bounds__(1024) void gru_k(const float* __restrict__ wihT,
    const float* __restrict__ whhV, const float* __restrict__ bhh,
    const float* __restrict__ ai, const float* __restrict__ fpost,
    const float* __restrict__ pwV, float* __restrict__ out,
    float* __restrict__ hs, float* __restrict__ ghs, int* __restrict__ idxs,
    int t0)
{
    float* out_post = out + 1048576;
    float* out_h    = out + 2097152;
    float* out_z    = out + 2228224;
    int b   = blockIdx.x;
    int tid = threadIdx.x;
    __shared__ __align__(16) float h[128];
    __shared__ float gi[384], gh[384];
    __shared__ int idx[32];
    if (t0 == 0) {
        if (tid < 128) h[tid] = 0.f;
        if (tid >= 512 && tid < 896) gh[tid - 512] = bhh[tid - 512]; // gh(0)
    } else {
        if (tid < 128) h[tid] = hs[b * 128 + tid];
        if (tid >= 512 && tid < 896) gh[tid - 512] = ghs[b * 384 + tid - 512];
        if (tid < 32) idx[tid] = idxs[b * 32 + tid];
    }
    __syncthreads();

    const float4* h4  = (const float4*)h;
    const float4* wv4 = (const float4*)whhV;
    const float4* pv4 = (const float4*)pwV;

    for (int tt = 0; tt < 32; tt++) {
        int t = t0 + tt;
        int n = b * 64 + t;
        // ---- P1: gi(t) = ai(t) + one-hot gather over idx(t-1) ----
        if (tid < 384) {
            float a = ai[(size_t)n * 384 + tid];
            if (t > 0) {
#pragma unroll 8
                for (int c = 0; c < 32; c++)
                    a += wihT[(size_t)(c * 32 + idx[c]) * 384 + tid];
            }
            gi[tid] = a;
        }
        __syncthreads();                                    // B1
        // ---- P2: h(t) from gi(t), gh(t) ----
        if (tid < 128) {
            float r  = sigm_f(gi[tid] + gh[tid]);
            float u  = sigm_f(gi[128 + tid] + gh[128 + tid]);
            float nn = tanhf(gi[256 + tid] + r * gh[256 + tid]);
            float hn = (1.f - u) * nn + u * h[tid];
            h[tid] = hn;
            out_h[(size_t)n * 128 + tid] = hn;
        }
        __syncthreads();                                    // B2
        // ---- P3a: post(t) + argmax -> idx(t)   [tid < 512]
        // ---- P3b: gh(t+1) = bhh + whhV.h(t)    [512 <= tid < 896]
        if (tid < 512) {
            float a0 = fpost[(size_t)n * 1024 + tid];
            float a1 = fpost[(size_t)n * 1024 + 512 + tid];
#pragma unroll 16
            for (int k4 = 0; k4 < 32; k4++) {
                float4 hq = h4[k4];                  // broadcast, reused x2
                float4 w0 = pv4[k4 * 1024 + tid];
                float4 w1 = pv4[k4 * 1024 + 512 + tid];
                a0 += w0.x*hq.x + w0.y*hq.y + w0.z*hq.z + w0.w*hq.w;
                a1 += w1.x*hq.x + w1.y*hq.y + w1.z*hq.z + w1.w*hq.w;
            }
            out_post[(size_t)n * 1024 + tid]       = a0;
            out_post[(size_t)n * 1024 + 512 + tid] = a1;

            // first-max argmax over each 32-lane chunk, in-register butterfly
            float b0 = a0, b1 = a1;
            int i0 = tid & 31, i1 = tid & 31;
#pragma unroll
            for (int m = 16; m >= 1; m >>= 1) {
                float ob0 = __shfl_xor(b0, m);
                int   oi0 = __shfl_xor(i0, m);
                float ob1 = __shfl_xor(b1, m);
                int   oi1 = __shfl_xor(i1, m);
                if (ob0 > b0 || (ob0 == b0 && oi0 < i0)) { b0 = ob0; i0 = oi0; }
                if (ob1 > b1 || (ob1 == b1 && oi1 < i1)) { b1 = ob1; i1 = oi1; }
            }
            out_z[(size_t)n * 1024 + tid]       = ((tid & 31) == i0) ? 1.f : 0.f;
            out_z[(size_t)n * 1024 + 512 + tid] = ((tid & 31) == i1) ? 1.f : 0.f;
            if ((tid & 31) == 0) {
                idx[tid >> 5]        = i0;
                idx[(tid >> 5) + 16] = i1;
            }
        } else if (tid < 896) {
            int r = tid - 512;                       // 0..383
            float a2 = bhh[r];
#pragma unroll 8
            for (int k4 = 0; k4 < 32; k4++) {
                float4 wq = wv4[k4 * 384 + r];       // coalesced 16B/lane
                float4 hq = h4[k4];                  // broadcast b128
                a2 += wq.x*hq.x + wq.y*hq.y + wq.z*hq.z + wq.w*hq.w;
            }
            gh[r] = a2;
        }
        __syncthreads();                                    // B3
    }
    // ---- persist state for next 32-step launch ----
    if (t0 == 0) {
        if (tid < 128) hs[b * 128 + tid] = h[tid];
        else if (tid >= 512 && tid < 896) ghs[b * 384 + tid - 512] = gh[tid - 512];
        if (tid < 32) idxs[b * 32 + tid] = idx[tid];
    }
}

// ---------------------------------------------------------------------------
extern "C" void kernel_launch(void* const* d_in, const int* in_sizes, int n_in,
                              void* d_out, int out_size, void* d_ws, size_t ws_size,
                              hipStream_t stream)
{
    const float* states  = (const float*)d_in[0];
    const float* actions = (const float*)d_in[1];
    const float* c1w = (const float*)d_in[2];  const float* c1b = (const float*)d_in[3];
    const float* l1g = (const float*)d_in[4];  const float* l1b = (const float*)d_in[5];
    const float* c2w = (const float*)d_in[6];  const float* c2b = (const float*)d_in[7];
    const float* l2g = (const float*)d_in[8];  const float* l2b = (const float*)d_in[9];
    const float* c3w = (const float*)d_in[10]; const float* c3b = (const float*)d_in[11];
    const float* l3g = (const float*)d_in[12]; const float* l3b = (const float*)d_in[13];
    const float* c4w = (const float*)d_in[14]; const float* c4b = (const float*)d_in[15];
    const float* l4g = (const float*)d_in[16]; const float* l4b = (const float*)d_in[17];
    const float* fcw = (const float*)d_in[18]; const float* fcb = (const float*)d_in[19];
    const float* wih = (const float*)d_in[20]; const float* whh = (const float*)d_in[21];
    const float* bih = (const float*)d_in[22]; const float* bhh = (const float*)d_in[23];
    const float* prw = (const float*)d_in[24]; const float* prb = (const float*)d_in[25];
    const float* pw  = (const float*)d_in[26]; const float* pb  = (const float*)d_in[27];

    float* out = (float*)d_out;
    float* ws  = (float*)d_ws;

    // ---- adaptive chunking: largest S whose footprint fits ws_size --------
    // footprint = (S*49152 + fixed 3,859,968) floats
    size_t S = 64;
    {
        const size_t cands[4] = {1024, 512, 256, 128};
        for (int i = 0; i < 4; i++) {
            size_t need = (cands[i] * 49152ull + 3859968ull) * 4ull;
            if (need <= ws_size) { S = cands[i]; break; }
        }
    }
    int C = (int)(1024 / S);

    float* bufA  = ws;                       // S*32768
    float* bufB  = bufA + S * 32768;         // S*16384
    float* feats = bufB + S * 16384;         //   262,144
    float* fpost = feats + 262144;           // 1,048,576
    float* aibuf = fpost + 1048576;          //   393,216
    float* wihT  = aibuf + 393216;           //   393,216
    float* fcwT  = wihT + 393216;            // 1,048,576
    float* whhV  = fcwT + 1048576;           //    49,152
    float* pwV   = whhV + 49152;             //   131,072
    float* c4wT  = pwV + 131072;             //   524,288
    float* hs    = c4wT + 524288;            //     2,048
    float* ghs   = hs + 2048;                //     6,144
    int*   idxs  = (int*)(ghs + 6144);       //       512 ints

    trfc_k<<<dim3(128, 8), 256, 0, stream>>>(fcw, fcwT);
    tr_whh_k<<<192, 256, 0, stream>>>(whh, whhV);
    tr_pw_k<<<512, 256, 0, stream>>>(pw, pwV);
    tr_c4_k<<<2048, 256, 0, stream>>>(c4w, c4wT);

    for (int cc = 0; cc < C; cc++) {
        size_t n0 = (size_t)cc * S;
        conv1_k<<<dim3((unsigned)S, 4), 256, 0, stream>>>(states + n0 * 12288, c1w, c1b, bufA);
        ln_fuse_k<<<(unsigned)S, 256, 0, stream>>>(bufA, l1g, l1b, 32768);
        conv2_r<<<(unsigned)S, 256, 0, stream>>>(bufA, c2w, c2b, l2g, l2b, bufB);
        conv3_r<<<(unsigned)S, 256, 0, stream>>>(bufB, c3w, c3b, l3g, l3b, bufA);
        conv4_f<<<(unsigned)S, 256, 0, stream>>>(bufA, c4wT, c4b, l4g, l4b, bufB);
        fc_k2<<<(unsigned)(S / 8), 256, 0, stream>>>(bufB, fcwT, fcb, feats + n0 * 256);
    }

    fpost_k<<<256, 256, 0, stream>>>(feats, pw, pb, fpost);
    ai_k<<<dim3(1024, 3), 128, 0, stream>>>(actions, wih, bih, aibuf);
    tr_k<<<1536, 256, 0, stream>>>(wih, wihT);

    for (int t0 = 0; t0 < 64; t0 += 32)
        gru_k<<<16, 1024, 0, stream>>>(wihT, whhV, bhh, aibuf, fpost, pwV, out,
                                       hs, ghs, idxs, t0);
    prior_k<<<256, 256, 0, stream>>>(out + 2097152, prw, prb, out);
}

// Round 16
// 2455.571 us; speedup vs baseline: 1.1331x; 1.1331x over previous
//
#include <hip/hip_runtime.h>
#include <math.h>

// ---------------------------------------------------------------------------
// RSSM: B=16, T=64 (bt=1024), encoder 3->32->64->128->256 (k4 s2 p1) with
// full-tensor LayerNorm+SiLU per layer, fc 4096->256, GRU(1030->128),
// prior 128->1024, post 384->1024, z = per-32-chunk argmax one-hot.
// All fp32: one flipped argmax = 1.0 error in z -> low precision in the
// logit path is fatal.
// R19 changes (from profile): R18's s_load weight path REGRESSED conv3
// (461->793us): 512 distinct weight floats/ch/wave through the scalar
// cache serializes (1:1 FMA:fetch -- the same lesson as R5). Reverted to
// the R17 LDS-broadcast conv3 (461us proven) and fixed its one defect:
// weight staging wrote at lane-stride 32B (4 banks/64 lanes -> 16-way
// b128 write conflicts, bulk of its 35M). New per-chunk layout [oc][64]
// (matches global row order) -> staging is LINEAR in tid (conv2's proven
// pattern); reads stay half-wave-uniform broadcast (free 2-way).
// ---------------------------------------------------------------------------

__device__ __forceinline__ float silu_f(float t){ return t / (1.f + __expf(-t)); }
__device__ __forceinline__ float sigm_f(float x){ return 1.f / (1.f + expf(-x)); }

// Block-level mean/rstd over m values; each thread contributes (s, s2).
__device__ __forceinline__ void block_stats_256(float s, float s2, int m,
                                                float& mean, float& rstd)
{
    __shared__ float red[8];
#pragma unroll
    for (int off = 32; off > 0; off >>= 1) {
        s  += __shfl_down(s, off);
        s2 += __shfl_down(s2, off);
    }
    int wv = threadIdx.x >> 6;
    if ((threadIdx.x & 63) == 0) { red[wv] = s; red[4 + wv] = s2; }
    __syncthreads();
    if (threadIdx.x == 0) {
        float S  = (red[0] + red[1]) + (red[2] + red[3]);
        float S2 = (red[4] + red[5]) + (red[6] + red[7]);
        float mu = S / m;
        float var = S2 / m - mu * mu;
        red[0] = mu;
        red[1] = rsqrtf(var + 1e-5f);
    }
    __syncthreads();
    mean = red[0]; rstd = red[1];
}

// ---------------- fused LayerNorm+SiLU, one block per sample ---------------
__global__ __launch_bounds__(256) void ln_fuse_k(float* __restrict__ x,
    const float* __restrict__ g, const float* __restrict__ b, int m)
{
    int n = blockIdx.x;
    float* p = x + (size_t)n * m;
    float s = 0.f, s2 = 0.f;
    for (int i = threadIdx.x * 4; i < m; i += 1024) {
        float4 v = *(const float4*)(p + i);
        s  += (v.x + v.y) + (v.z + v.w);
        s2 += (v.x*v.x + v.y*v.y) + (v.z*v.z + v.w*v.w);
    }
    float mean, rstd;
    block_stats_256(s, s2, m, mean, rstd);
    for (int i = threadIdx.x * 4; i < m; i += 1024) {
        float4 v  = *(float4*)(p + i);
        float4 gv = *(const float4*)(g + i);
        float4 bv = *(const float4*)(b + i);
        v.x = silu_f((v.x - mean) * rstd * gv.x + bv.x);
        v.y = silu_f((v.y - mean) * rstd * gv.y + bv.y);
        v.z = silu_f((v.z - mean) * rstd * gv.z + bv.z);
        v.w = silu_f((v.w - mean) * rstd * gv.w + bv.w);
        *(float4*)(p + i) = v;
    }
}

// ------------------------- conv1: 3x64x64 -> 32x32x32 ----------------------
__global__ __launch_bounds__(256) void conv1_k(const float* __restrict__ in,
    const float* __restrict__ w, const float* __restrict__ bias, float* __restrict__ out)
{
    int n  = blockIdx.x;                 // chunk-local sample
    int yq = blockIdx.y;                 // 4 y-quarters
    int tx = threadIdx.x & 31;
    int ty = threadIdx.x >> 5;           // 0..7
    int y  = yq * 8 + ty;                // 0..31
    const float* ip = in + (size_t)n * 12288;

    float okf[16]; int offs[16];
#pragma unroll
    for (int ky = 0; ky < 4; ky++) {
        int yy = 2 * y - 1 + ky;
        bool yok = ((unsigned)yy < 64u);
#pragma unroll
        for (int kx = 0; kx < 4; kx++) {
            int xx = 2 * tx - 1 + kx;
            bool ok = yok && ((unsigned)xx < 64u);
            okf[ky*4+kx]  = ok ? 1.f : 0.f;
            offs[ky*4+kx] = ok ? yy * 64 + xx : 0;
        }
    }
    float iv[48];
#pragma unroll
    for (int c = 0; c < 3; c++)
#pragma unroll
        for (int q = 0; q < 16; q++)
            iv[c*16+q] = ip[c*4096 + offs[q]] * okf[q];

    float* op = out + (size_t)n * 32768 + y * 32 + tx;
#pragma unroll 4
    for (int oc = 0; oc < 32; oc++) {           // oc uniform -> weights s_load
        float acc = bias[oc];
        const float* wp = w + oc * 48;
#pragma unroll
        for (int q = 0; q < 48; q++) acc += iv[q] * wp[q];
        op[oc * 1024] = acc;
    }
}

// ------- conv2 + LN2 + SiLU: 32x32x32 -> 64x16x16 -------------------------
__global__ __launch_bounds__(256) void conv2_r(const float* __restrict__ in,
    const float* __restrict__ w, const float* __restrict__ bias,
    const float* __restrict__ lg, const float* __restrict__ lb,
    float* __restrict__ out)
{
    __shared__ __align__(16) float lds[8208];     // 4*1028 input + 4096 wt
    int n  = blockIdx.x;
    int tid = threadIdx.x;
    int wv  = tid >> 6;
    int g   = wv >> 1;                            // oc half 0/1
    int s   = ((wv & 1) << 6) | (tid & 63);       // 0..127
    int x   = s & 15, y0 = s >> 4;                // x 0..15, y0 0..7
    const float* ip = in + (size_t)n * 32768;

    int offs[2][16];
#pragma unroll
    for (int p = 0; p < 2; p++) {
        int y = y0 + 8 * p;
#pragma unroll
        for (int ky = 0; ky < 4; ky++) {
            int yi = 2 * y - 1 + ky;
#pragma unroll
            for (int kx = 0; kx < 4; kx++) {
                int xi = 2 * x - 1 + kx;
                bool ok = ((unsigned)yi < 32u) && ((unsigned)xi < 32u);
                int rot = ((xi >> 2) + (yi & 7)) & 7;
                int foff = yi * 32 + rot * 4 + (xi & 3);
                offs[p][ky*4+kx] = ok ? (4 + foff) * 4 : 0;   // bytes; 0 = zero slot
            }
        }
    }
    if (tid < 16) lds[(tid >> 2) * 1028 + (tid & 3)] = 0.f;   // zero slots

    float acc0[32], acc1[32];
#pragma unroll
    for (int i = 0; i < 32; i++) { float bv = bias[g*32 + i]; acc0[i] = bv; acc1[i] = bv; }

#pragma unroll 1
    for (int ch = 0; ch < 8; ch++) {              // 8 chunks x 4 channels
        __syncthreads();
        {   // stage input: 4 ch x 1024 fl, rotated rows
            const float4* gs = (const float4*)(ip + (ch << 12));
#pragma unroll
            for (int k = 0; k < 4; k++) {
                int gid = tid + (k << 8);         // 0..1023 f4s
                int cc = gid >> 8, r = (gid >> 3) & 31, s4 = gid & 7;
                int rs = (s4 + (r & 7)) & 7;
                *(float4*)&lds[cc*1028 + 4 + r*32 + rs*4] = gs[gid];
            }
            // stage weights: 4 ch x 64 oc x 16 (linear in tid)
            int oc = tid >> 2, i4 = tid & 3;
            const float* wg = w + (size_t)oc * 512 + (ch << 6) + i4 * 4;
#pragma unroll
            for (int cc = 0; cc < 4; cc++)
                *(float4*)&lds[4112 + cc*1024 + oc*16 + i4*4] =
                    *(const float4*)(wg + cc * 16);
        }
        __syncthreads();
#pragma unroll 1
        for (int cc = 0; cc < 4; cc++) {
            const char* cb = (const char*)lds + cc * 4112;
            float iv0[16], iv1[16];
#pragma unroll
            for (int q = 0; q < 16; q++) {
                iv0[q] = *(const float*)(cb + offs[0][q]);
                iv1[q] = *(const float*)(cb + offs[1][q]);
            }
            const float* wb = &lds[4112 + cc*1024 + g*512];   // wave-uniform base
#pragma unroll
            for (int o = 0; o < 32; o++) {
                float wt[16];
                *(float4*)&wt[0]  = *(const float4*)(wb + o*16);
                *(float4*)&wt[4]  = *(const float4*)(wb + o*16 + 4);
                *(float4*)&wt[8]  = *(const float4*)(wb + o*16 + 8);
                *(float4*)&wt[12] = *(const float4*)(wb + o*16 + 12);
#pragma unroll
                for (int q = 0; q < 16; q++) {
                    acc0[o] = fmaf(iv0[q], wt[q], acc0[o]);
                    acc1[o] = fmaf(iv1[q], wt[q], acc1[o]);
                }
            }
        }
    }
    // ---- fused LN2 + SiLU over the block-resident 16384 values ----
    float s1 = 0.f, s2 = 0.f;
#pragma unroll
    for (int o = 0; o < 32; o++) {
        s1 += acc0[o] + acc1[o];
        s2 += acc0[o]*acc0[o] + acc1[o]*acc1[o];
    }
    float mean, rstd;
    block_stats_256(s1, s2, 16384, mean, rstd);

    float* op = out + (size_t)n * 16384;
#pragma unroll
    for (int o = 0; o < 32; o++) {
        int f0 = (g*32 + o) * 256 + y0*16 + x;
        int f1 = (g*32 + o) * 256 + (y0+8)*16 + x;
        op[f0] = silu_f((acc0[o] - mean) * rstd * lg[f0] + lb[f0]);
        op[f1] = silu_f((acc1[o] - mean) * rstd * lg[f1] + lb[f1]);
    }
}

// ------- conv3 + LN3 + SiLU: 64x16x16 -> 128x8x8 ---------------------------
// R19 = R17 structure (8 half-wave groups x 16 oc, 2 pos/thread, weights
// broadcast from LDS) with weight LDS layout [oc][64] so STAGING IS LINEAR
// in tid (was lane-stride 32B -> 16-way write conflicts). Reads broadcast,
// half-wave-uniform (free 2-way).
__global__ __launch_bounds__(256) void conv3_r(const float* __restrict__ in,
    const float* __restrict__ w, const float* __restrict__ bias,
    const float* __restrict__ lg, const float* __restrict__ lb,
    float* __restrict__ out)
{
    __shared__ __align__(16) float lds[9232];    // 4*260 input + 8192 wt
    int n   = blockIdx.x;
    int tid = threadIdx.x;
    int g   = tid >> 5;                  // 0..7 -> oc group (16 oc)
    int slot= tid & 31;
    int x   = slot & 7, y0 = slot >> 3;  // x 0..7, y0 0..3

    int offs[2][16];
#pragma unroll
    for (int p = 0; p < 2; p++) {
        int y = y0 + 4 * p;
#pragma unroll
        for (int ky = 0; ky < 4; ky++) {
            int yi = 2 * y - 1 + ky;
#pragma unroll
            for (int kx = 0; kx < 4; kx++) {
                int xi = 2 * x - 1 + kx;
                bool ok = ((unsigned)yi < 16u) && ((unsigned)xi < 16u);
                int rot = ((xi >> 2) + (yi & 3)) & 3;
                int foff = yi * 16 + rot * 4 + (xi & 3);
                offs[p][ky*4+kx] = ok ? (4 + foff) * 4 : 0;   // bytes; 0 = zero slot
            }
        }
    }
    if (tid < 16) lds[(tid >> 2) * 260 + (tid & 3)] = 0.f;    // zero slots

    float acc0[16], acc1[16];
#pragma unroll
    for (int i = 0; i < 16; i++) { float bv = bias[g*16 + i]; acc0[i] = bv; acc1[i] = bv; }

    const float* ip = in + (size_t)n * 16384;
#pragma unroll 1
    for (int ch = 0; ch < 16; ch++) {             // 16 chunks x 4 channels
        __syncthreads();
        {   // stage input: 4 ch x 256 fl, rotated rows (1 f4/thread)
            const float4* gs = (const float4*)(ip + (ch << 10));
            int cc = tid >> 6, r = (tid >> 2) & 15, s4 = tid & 3;
            int rs = (s4 + (r & 3)) & 3;
            *(float4*)&lds[cc*260 + 4 + r*16 + rs*4] = gs[tid];
            // stage weights: [oc][64] layout, LINEAR writes (8 f4/thread)
            // F = float index in chunk-weight region; oc = F>>6, j = F&63;
            // src = w[oc][ch*4 .. ch*4+4) contiguous 64 floats.
#pragma unroll
            for (int k = 0; k < 8; k++) {
                int F  = (tid + (k << 8)) << 2;   // 0,4,..,8188
                int oc = F >> 6, j = F & 63;
                *(float4*)&lds[1040 + F] =
                    *(const float4*)(w + (size_t)oc * 1024 + (ch << 6) + j);
            }
        }
        __syncthreads();
#pragma unroll 1
        for (int cc = 0; cc < 4; cc++) {
            const char* cb = (const char*)lds + cc * 1040;
            float iv0[16], iv1[16];
#pragma unroll
            for (int q = 0; q < 16; q++) {
                iv0[q] = *(const float*)(cb + offs[0][q]);
                iv1[q] = *(const float*)(cb + offs[1][q]);
            }
            // weights for oc = g*16+o at lds[1040 + oc*64 + cc*16 + q]
            const float* wb = &lds[1040 + (g*16)*64 + cc*16];  // half-wave uniform
#pragma unroll
            for (int o = 0; o < 16; o++) {
                float wt[16];
                *(float4*)&wt[0]  = *(const float4*)(wb + o*64);
                *(float4*)&wt[4]  = *(const float4*)(wb + o*64 + 4);
                *(float4*)&wt[8]  = *(const float4*)(wb + o*64 + 8);
                *(float4*)&wt[12] = *(const float4*)(wb + o*64 + 12);
#pragma unroll
                for (int q = 0; q < 16; q++) {
                    acc0[o] = fmaf(iv0[q], wt[q], acc0[o]);
                    acc1[o] = fmaf(iv1[q], wt[q], acc1[o]);
                }
            }
        }
    }
    // ---- fused LN3 + SiLU over the block-resident 8192 values ----
    float s1 = 0.f, s2 = 0.f;
#pragma unroll
    for (int o = 0; o < 16; o++) {
        s1 += acc0[o] + acc1[o];
        s2 += acc0[o]*acc0[o] + acc1[o]*acc1[o];
    }
    float mean, rstd;
    block_stats_256(s1, s2, 8192, mean, rstd);

    float* op = out + (size_t)n * 8192;
#pragma unroll
    for (int o = 0; o < 16; o++) {
        int f0 = (g*16 + o) * 64 + slot;
        int f1 = (g*16 + o) * 64 + slot + 32;
        op[f0] = silu_f((acc0[o] - mean) * rstd * lg[f0] + lb[f0]);
        op[f1] = silu_f((acc1[o] - mean) * rstd * lg[f1] + lb[f1]);
    }
}

// ----- c4wT[c][oc][q] = conv4_w[oc][c*16+q]  (coalesced per-channel rows) --
__global__ __launch_bounds__(256) void tr_c4_k(const float* __restrict__ w,
                                               float* __restrict__ wt)
{
    int gi = blockIdx.x * 256 + threadIdx.x;     // 0..524287
    int q  = gi & 15;
    int t  = gi >> 4;                            // c*256 + oc
    int oc = t & 255;
    int c  = t >> 8;
    wt[gi] = w[(size_t)oc * 2048 + c * 16 + q];
}

// ----------------- conv4 + LN4 + SiLU: 128x8x8 -> 256x4x4 ------------------
__global__ __launch_bounds__(256) void conv4_f(const float* __restrict__ in,
    const float* __restrict__ wT, const float* __restrict__ bias,
    const float* __restrict__ g, const float* __restrict__ bet, float* __restrict__ out)
{
    int n  = blockIdx.x;
    int oc = threadIdx.x;                 // 0..255
    const float* ip = in + (size_t)n * 8192;

    float acc[16];
#pragma unroll
    for (int s = 0; s < 16; s++) acc[s] = bias[oc];

#pragma unroll 2
    for (int c = 0; c < 128; c++) {
        const float* ic = ip + c * 64;     // uniform base -> s_load, CSE'd
        const float4* wp = (const float4*)(wT + ((size_t)c * 256 + oc) * 16);
        float wf[16];
        *(float4*)&wf[0]  = wp[0];         // coalesced: lane stride 64B
        *(float4*)&wf[4]  = wp[1];
        *(float4*)&wf[8]  = wp[2];
        *(float4*)&wf[12] = wp[3];
#pragma unroll
        for (int y = 0; y < 4; y++)
#pragma unroll
        for (int x = 0; x < 4; x++) {
            float a = acc[y * 4 + x];
#pragma unroll
            for (int ky = 0; ky < 4; ky++) {
                int yy = 2 * y - 1 + ky;
                if (yy < 0 || yy > 7) continue;      // folds at compile time
#pragma unroll
                for (int kx = 0; kx < 4; kx++) {
                    int xx = 2 * x - 1 + kx;
                    if (xx < 0 || xx > 7) continue;
                    a += wf[ky * 4 + kx] * ic[yy * 8 + xx];
                }
            }
            acc[y * 4 + x] = a;
        }
    }
    float s = 0.f, s2 = 0.f;
#pragma unroll
    for (int q = 0; q < 16; q++) { s += acc[q]; s2 += acc[q] * acc[q]; }
    float mean, rstd;
    block_stats_256(s, s2, 4096, mean, rstd);

    float* op = out + (size_t)n * 4096;
#pragma unroll
    for (int q = 0; q < 16; q++) {
        int flat = oc * 16 + q;
        float v = (acc[q] - mean) * rstd * g[flat] + bet[flat];
        op[flat] = silu_f(v);
    }
}

// -------- transpose fc_w [256][4096] -> fcwT [4096][256] (LDS-tiled) -------
__global__ __launch_bounds__(256) void trfc_k(const float* __restrict__ w,
                                              float* __restrict__ wt)
{
    __shared__ float t[32][33];
    int bk = blockIdx.x * 32;             // k dim (4096)
    int bj = blockIdx.y * 32;             // j dim (256)
    int lx = threadIdx.x & 31, ly = threadIdx.x >> 5;   // 32 x 8
#pragma unroll
    for (int s = 0; s < 4; s++)
        t[ly + 8*s][lx] = w[(size_t)(bj + ly + 8*s) * 4096 + bk + lx];
    __syncthreads();
#pragma unroll
    for (int s = 0; s < 4; s++)
        wt[(size_t)(bk + ly + 8*s) * 256 + bj + lx] = t[lx][ly + 8*s];
}

// ---------------- fc: [S,4096] @ wT[4096][256], coalesced ------------------
__global__ __launch_bounds__(256) void fc_k2(const float* __restrict__ a,
    const float* __restrict__ wT, const float* __restrict__ bias, float* __restrict__ o)
{
    int n0 = blockIdx.x * 8;              // chunk-local rows
    int j  = threadIdx.x;
    float acc[8];
#pragma unroll
    for (int r = 0; r < 8; r++) acc[r] = 0.f;
    for (int k = 0; k < 4096; k += 4) {
        float wv0 = wT[(size_t)k * 256 + j];
        float wv1 = wT[(size_t)(k+1) * 256 + j];
        float wv2 = wT[(size_t)(k+2) * 256 + j];
        float wv3 = wT[(size_t)(k+3) * 256 + j];
#pragma unroll
        for (int r = 0; r < 8; r++) {
            const float* ar = a + (size_t)(n0 + r) * 4096 + k;   // uniform -> s_load x4
            acc[r] += wv0*ar[0] + wv1*ar[1] + wv2*ar[2] + wv3*ar[3];
        }
    }
    float bj = bias[j];
#pragma unroll
    for (int r = 0; r < 8; r++) o[(size_t)(n0 + r) * 256 + j] = acc[r] + bj;
}

// ----------- Fpost[n,j] = post_b[j] + feats[n,:] @ post_w[j,128:384] -------
__global__ __launch_bounds__(256) void fpost_k(const float* __restrict__ f,
    const float* __restrict__ w, const float* __restrict__ bias, float* __restrict__ o)
{
    int n0 = blockIdx.x * 4;
    int tid = threadIdx.x;
    float acc[4][4];
#pragma unroll
    for (int r = 0; r < 4; r++)
#pragma unroll
        for (int jj = 0; jj < 4; jj++) acc[r][jj] = 0.f;
    for (int k = 0; k < 256; k += 4) {
        float4 wv[4];
#pragma unroll
        for (int jj = 0; jj < 4; jj++)
            wv[jj] = *(const float4*)(w + (size_t)(tid + jj * 256) * 384 + 128 + k);
#pragma unroll
        for (int r = 0; r < 4; r++) {
            const float* fr = f + (size_t)(n0 + r) * 256 + k;    // uniform
            float a0 = fr[0], a1 = fr[1], a2 = fr[2], a3 = fr[3];
#pragma unroll
            for (int jj = 0; jj < 4; jj++)
                acc[r][jj] += wv[jj].x*a0 + wv[jj].y*a1 + wv[jj].z*a2 + wv[jj].w*a3;
        }
    }
#pragma unroll
    for (int jj = 0; jj < 4; jj++) {
        float bj = bias[tid + jj * 256];
#pragma unroll
        for (int r = 0; r < 4; r++)
            o[(size_t)(n0 + r) * 1024 + tid + jj * 256] = acc[r][jj] + bj;
    }
}

// ----------- prior[n,j] = prior_b[j] + h[n,:] @ prior_w[j,:] ---------------
__global__ __launch_bounds__(256) void prior_k(const float* __restrict__ h,
    const float* __restrict__ w, const float* __restrict__ bias, float* __restrict__ o)
{
    int n0 = blockIdx.x * 4;
    int tid = threadIdx.x;
    float acc[4][4];
#pragma unroll
    for (int r = 0; r < 4; r++)
#pragma unroll
        for (int jj = 0; jj < 4; jj++) acc[r][jj] = 0.f;
    for (int k = 0; k < 128; k += 4) {
        float4 wv[4];
#pragma unroll
        for (int jj = 0; jj < 4; jj++)
            wv[jj] = *(const float4*)(w + (size_t)(tid + jj * 256) * 128 + k);
#pragma unroll
        for (int r = 0; r < 4; r++) {
            const float* hr = h + (size_t)(n0 + r) * 128 + k;    // uniform
            float a0 = hr[0], a1 = hr[1], a2 = hr[2], a3 = hr[3];
#pragma unroll
            for (int jj = 0; jj < 4; jj++)
                acc[r][jj] += wv[jj].x*a0 + wv[jj].y*a1 + wv[jj].z*a2 + wv[jj].w*a3;
        }
    }
#pragma unroll
    for (int jj = 0; jj < 4; jj++) {
        float bj = bias[tid + jj * 256];
#pragma unroll
        for (int r = 0; r < 4; r++)
            o[(size_t)(n0 + r) * 1024 + tid + jj * 256] = acc[r][jj] + bj;
    }
}

// ----------- Ai[n,j] = bih[j] + actions[n,:] @ wih[j,1024:1030] ------------
__global__ __launch_bounds__(128) void ai_k(const float* __restrict__ act,
    const float* __restrict__ wih, const float* __restrict__ bih, float* __restrict__ o)
{
    int n = blockIdx.x;
    int j = blockIdx.y * 128 + threadIdx.x;     // 0..383
    const float* ar = act + (size_t)n * 6;       // uniform
    const float* wr = wih + (size_t)j * 1030 + 1024;
    float acc = bih[j];
#pragma unroll
    for (int k = 0; k < 6; k++) acc += ar[k] * wr[k];
    o[(size_t)n * 384 + j] = acc;
}

// ----------- wihT[k,j] = wih[j,k]  (z-part only, k<1024) -------------------
__global__ __launch_bounds__(256) void tr_k(const float* __restrict__ wih,
                                            float* __restrict__ wt)
{
    int g = blockIdx.x * 256 + threadIdx.x;      // 0..393215
    int k = g / 384;
    int j = g - k * 384;
    wt[g] = wih[(size_t)j * 1030 + k];
}

// ----- whhV[k4][j][c] = whh[j][4*k4+c]  (float4-packed, coalesced) ---------
__global__ __launch_bounds__(256) void tr_whh_k(const float* __restrict__ whh,
                                                float* __restrict__ wt)
{
    int g = blockIdx.x * 256 + threadIdx.x;      // 0..49151
    int c  = g & 3;
    int jk = g >> 2;                             // 0..12287
    int j  = jk % 384;
    int k4 = jk / 384;                           // 0..31
    wt[g] = whh[(size_t)j * 128 + k4 * 4 + c];
}

// ----- pwV[k4][j][c] = post_w[j][4*k4+c] (h-cols only, float4-packed) ------
__global__ __launch_bounds__(256) void tr_pw_k(const float* __restrict__ pw,
                                               float* __restrict__ wt)
{
    int g = blockIdx.x * 256 + threadIdx.x;      // 0..131071
    int c  = g & 3;
    int jk = g >> 2;                             // 0..32767
    int j  = jk & 1023;
    int k4 = jk >> 10;                           // 0..31
    wt[g] = pw[(size_t)j * 384 + k4 * 4 + c];
}

// ------------------- GRU recurrence (1 block / sample, 32 steps) -----------
__global__ __launch_bounds__(1024) void gru_k(const float* __restrict__ wihT,
    const float* __restrict__ whhV, const float* __restrict__ bhh,
    const float* __restrict__ ai, const float* __restrict__ fpost,
    const float* __restrict__ pwV, float* __restrict__ out,
    float* __restrict__ hs, float* __restrict__ ghs, int* __restrict__ idxs,
    int t0)
{
    float* out_post = out + 1048576;
    float* out_h    = out + 2097152;
    float* out_z    = out + 2228224;
    int b   = blockIdx.x;
    int tid = threadIdx.x;
    __shared__ __align__(16) float h[128];
    __shared__ float gi[384], gh[384];
    __shared__ int idx[32];
    if (t0 == 0) {
        if (tid < 128) h[tid] = 0.f;
        if (tid >= 512 && tid < 896) gh[tid - 512] = bhh[tid - 512]; // gh(0)
    } else {
        if (tid < 128) h[tid] = hs[b * 128 + tid];
        if (tid >= 512 && tid < 896) gh[tid - 512] = ghs[b * 384 + tid - 512];
        if (tid < 32) idx[tid] = idxs[b * 32 + tid];
    }
    __syncthreads();

    const float4* h4  = (const float4*)h;
    const float4* wv4 = (const float4*)whhV;
    const float4* pv4 = (const float4*)pwV;

    for (int tt = 0; tt < 32; tt++) {
        int t = t0 + tt;
        int n = b * 64 + t;
        // ---- P1: gi(t) = ai(t) + one-hot gather over idx(t-1) ----
        if (tid < 384) {
            float a = ai[(size_t)n * 384 + tid];
            if (t > 0) {
#pragma unroll 8
                for (int c = 0; c < 32; c++)
                    a += wihT[(size_t)(c * 32 + idx[c]) * 384 + tid];
            }
            gi[tid] = a;
        }
        __syncthreads();                                    // B1
        // ---- P2: h(t) from gi(t), gh(t) ----
        if (tid < 128) {
            float r  = sigm_f(gi[tid] + gh[tid]);
            float u  = sigm_f(gi[128 + tid] + gh[128 + tid]);
            float nn = tanhf(gi[256 + tid] + r * gh[256 + tid]);
            float hn = (1.f - u) * nn + u * h[tid];
            h[tid] = hn;
            out_h[(size_t)n * 128 + tid] = hn;
        }
        __syncthreads();                                    // B2
        // ---- P3a: post(t) + argmax -> idx(t)   [tid < 512]
        // ---- P3b: gh(t+1) = bhh + whhV.h(t)    [512 <= tid < 896]
        if (tid < 512) {
            float a0 = fpost[(size_t)n * 1024 + tid];
            float a1 = fpost[(size_t)n * 1024 + 512 + tid];
#pragma unroll 16
            for (int k4 = 0; k4 < 32; k4++) {
                float4 hq = h4[k4];                  // broadcast, reused x2
                float4 w0 = pv4[k4 * 1024 + tid];
                float4 w1 = pv4[k4 * 1024 + 512 + tid];
                a0 += w0.x*hq.x + w0.y*hq.y + w0.z*hq.z + w0.w*hq.w;
                a1 += w1.x*hq.x + w1.y*hq.y + w1.z*hq.z + w1.w*hq.w;
            }
            out_post[(size_t)n * 1024 + tid]       = a0;
            out_post[(size_t)n * 1024 + 512 + tid] = a1;

            // first-max argmax over each 32-lane chunk, in-register butterfly
            float b0 = a0, b1 = a1;
            int i0 = tid & 31, i1 = tid & 31;
#pragma unroll
            for (int m = 16; m >= 1; m >>= 1) {
                float ob0 = __shfl_xor(b0, m);
                int   oi0 = __shfl_xor(i0, m);
                float ob1 = __shfl_xor(b1, m);
                int   oi1 = __shfl_xor(i1, m);
                if (ob0 > b0 || (ob0 == b0 && oi0 < i0)) { b0 = ob0; i0 = oi0; }
                if (ob1 > b1 || (ob1 == b1 && oi1 < i1)) { b1 = ob1; i1 = oi1; }
            }
            out_z[(size_t)n * 1024 + tid]       = ((tid & 31) == i0) ? 1.f : 0.f;
            out_z[(size_t)n * 1024 + 512 + tid] = ((tid & 31) == i1) ? 1.f : 0.f;
            if ((tid & 31) == 0) {
                idx[tid >> 5]        = i0;
                idx[(tid >> 5) + 16] = i1;
            }
        } else if (tid < 896) {
            int r = tid - 512;                       // 0..383
            float a2 = bhh[r];
#pragma unroll 8
            for (int k4 = 0; k4 < 32; k4++) {
                float4 wq = wv4[k4 * 384 + r];       // coalesced 16B/lane
                float4 hq = h4[k4];                  // broadcast b128
                a2 += wq.x*hq.x + wq.y*hq.y + wq.z*hq.z + wq.w*hq.w;
            }
            gh[r] = a2;
        }
        __syncthreads();                                    // B3
    }
    // ---- persist state for next 32-step launch ----
    if (t0 == 0) {
        if (tid < 128) hs[b * 128 + tid] = h[tid];
        else if (tid >= 512 && tid < 896) ghs[b * 384 + tid - 512] = gh[tid - 512];
        if (tid < 32) idxs[b * 32 + tid] = idx[tid];
    }
}

// ---------------------------------------------------------------------------
extern "C" void kernel_launch(void* const* d_in, const int* in_sizes, int n_in,
                              void* d_out, int out_size, void* d_ws, size_t ws_size,
                              hipStream_t stream)
{
    const float* states  = (const float*)d_in[0];
    const float* actions = (const float*)d_in[1];
    const float* c1w = (const float*)d_in[2];  const float* c1b = (const float*)d_in[3];
    const float* l1g = (const float*)d_in[4];  const float* l1b = (const float*)d_in[5];
    const float* c2w = (const float*)d_in[6];  const float* c2b = (const float*)d_in[7];
    const float* l2g = (const float*)d_in[8];  const float* l2b = (const float*)d_in[9];
    const float* c3w = (const float*)d_in[10]; const float* c3b = (const float*)d_in[11];
    const float* l3g = (const float*)d_in[12]; const float* l3b = (const float*)d_in[13];
    const float* c4w = (const float*)d_in[14]; const float* c4b = (const float*)d_in[15];
    const float* l4g = (const float*)d_in[16]; const float* l4b = (const float*)d_in[17];
    const float* fcw = (const float*)d_in[18]; const float* fcb = (const float*)d_in[19];
    const float* wih = (const float*)d_in[20]; const float* whh = (const float*)d_in[21];
    const float* bih = (const float*)d_in[22]; const float* bhh = (const float*)d_in[23];
    const float* prw = (const float*)d_in[24]; const float* prb = (const float*)d_in[25];
    const float* pw  = (const float*)d_in[26]; const float* pb  = (const float*)d_in[27];

    float* out = (float*)d_out;
    float* ws  = (float*)d_ws;

    // ---- adaptive chunking: largest S whose footprint fits ws_size --------
    // footprint = (S*49152 + fixed 3,859,968) floats
    size_t S = 64;
    {
        const size_t cands[4] = {1024, 512, 256, 128};
        for (int i = 0; i < 4; i++) {
            size_t need = (cands[i] * 49152ull + 3859968ull) * 4ull;
            if (need <= ws_size) { S = cands[i]; break; }
        }
    }
    int C = (int)(1024 / S);

    float* bufA  = ws;                       // S*32768
    float* bufB  = bufA + S * 32768;         // S*16384
    float* feats = bufB + S * 16384;         //   262,144
    float* fpost = feats + 262144;           // 1,048,576
    float* aibuf = fpost + 1048576;          //   393,216
    float* wihT  = aibuf + 393216;           //   393,216
    float* fcwT  = wihT + 393216;            // 1,048,576
    float* whhV  = fcwT + 1048576;           //    49,152
    float* pwV   = whhV + 49152;             //   131,072
    float* c4wT  = pwV + 131072;             //   524,288
    float* hs    = c4wT + 524288;            //     2,048
    float* ghs   = hs + 2048;                //     6,144
    int*   idxs  = (int*)(ghs + 6144);       //       512 ints

    trfc_k<<<dim3(128, 8), 256, 0, stream>>>(fcw, fcwT);
    tr_whh_k<<<192, 256, 0, stream>>>(whh, whhV);
    tr_pw_k<<<512, 256, 0, stream>>>(pw, pwV);
    tr_c4_k<<<2048, 256, 0, stream>>>(c4w, c4wT);

    for (int cc = 0; cc < C; cc++) {
        size_t n0 = (size_t)cc * S;
        conv1_k<<<dim3((unsigned)S, 4), 256, 0, stream>>>(states + n0 * 12288, c1w, c1b, bufA);
        ln_fuse_k<<<(unsigned)S, 256, 0, stream>>>(bufA, l1g, l1b, 32768);
        conv2_r<<<(unsigned)S, 256, 0, stream>>>(bufA, c2w, c2b, l2g, l2b, bufB);
        conv3_r<<<(unsigned)S, 256, 0, stream>>>(bufB, c3w, c3b, l3g, l3b, bufA);
        conv4_f<<<(unsigned)S, 256, 0, stream>>>(bufA, c4wT, c4b, l4g, l4b, bufB);
        fc_k2<<<(unsigned)(S / 8), 256, 0, stream>>>(bufB, fcwT, fcb, feats + n0 * 256);
    }

    fpost_k<<<256, 256, 0, stream>>>(feats, pw, pb, fpost);
    ai_k<<<dim3(1024, 3), 128, 0, stream>>>(actions, wih, bih, aibuf);
    tr_k<<<1536, 256, 0, stream>>>(wih, wihT);

    for (int t0 = 0; t0 < 64; t0 += 32)
        gru_k<<<16, 1024, 0, stream>>>(wihT, whhV, bhh, aibuf, fpost, pwV, out,
                                       hs, ghs, idxs, t0);
    prior_k<<<256, 256, 0, stream>>>(out + 2097152, prw, prb, out);
}

// Round 17
// 2381.246 us; speedup vs baseline: 1.1684x; 1.0312x over previous
//
#include <hip/hip_runtime.h>
#include <math.h>

// ---------------------------------------------------------------------------
// RSSM: B=16, T=64 (bt=1024), encoder 3->32->64->128->256 (k4 s2 p1) with
// full-tensor LayerNorm+SiLU per layer, fc 4096->256, GRU(1030->128),
// prior 128->1024, post 384->1024, z = per-32-chunk argmax one-hot.
// All fp32: one flipped argmax = 1.0 error in z -> low precision in the
// logit path is fatal.
// R20 changes (from profile+arithmetic): conv3 LDS pipe ~2x oversubscribed
// (per cc/wave: VALU 1024cy vs LDS 485cy x4 waves). Conflicts were NOT
// staging (R19 disproved) but the iv gathers: row stride 16 + stride-2
// taps => yi*16 mod 32 const => 32 addrs in 16 banks, rotation folds to
// ~8 => 4-way. Fix: (1) row stride 20 (2*20=40=8 mod 32 -> y-rows spread
// {0,8,16,24}, provably 2-way max); (2) taps per row are CONSECUTIVE
// (2x-1..2x+2) -> read b32+b64+b32 (3 instrs vs 4), OOB via zero-slot
// address select. iv cost/cc/wave 293->~142cy. Weight path unchanged.
// ---------------------------------------------------------------------------

__device__ __forceinline__ float silu_f(float t){ return t / (1.f + __expf(-t)); }
__device__ __forceinline__ float sigm_f(float x){ return 1.f / (1.f + expf(-x)); }

// Block-level mean/rstd over m values; each thread contributes (s, s2).
__device__ __forceinline__ void block_stats_256(float s, float s2, int m,
                                                float& mean, float& rstd)
{
    __shared__ float red[8];
#pragma unroll
    for (int off = 32; off > 0; off >>= 1) {
        s  += __shfl_down(s, off);
        s2 += __shfl_down(s2, off);
    }
    int wv = threadIdx.x >> 6;
    if ((threadIdx.x & 63) == 0) { red[wv] = s; red[4 + wv] = s2; }
    __syncthreads();
    if (threadIdx.x == 0) {
        float S  = (red[0] + red[1]) + (red[2] + red[3]);
        float S2 = (red[4] + red[5]) + (red[6] + red[7]);
        float mu = S / m;
        float var = S2 / m - mu * mu;
        red[0] = mu;
        red[1] = rsqrtf(var + 1e-5f);
    }
    __syncthreads();
    mean = red[0]; rstd = red[1];
}

// ---------------- fused LayerNorm+SiLU, one block per sample ---------------
__global__ __launch_bounds__(256) void ln_fuse_k(float* __restrict__ x,
    const float* __restrict__ g, const float* __restrict__ b, int m)
{
    int n = blockIdx.x;
    float* p = x + (size_t)n * m;
    float s = 0.f, s2 = 0.f;
    for (int i = threadIdx.x * 4; i < m; i += 1024) {
        float4 v = *(const float4*)(p + i);
        s  += (v.x + v.y) + (v.z + v.w);
        s2 += (v.x*v.x + v.y*v.y) + (v.z*v.z + v.w*v.w);
    }
    float mean, rstd;
    block_stats_256(s, s2, m, mean, rstd);
    for (int i = threadIdx.x * 4; i < m; i += 1024) {
        float4 v  = *(float4*)(p + i);
        float4 gv = *(const float4*)(g + i);
        float4 bv = *(const float4*)(b + i);
        v.x = silu_f((v.x - mean) * rstd * gv.x + bv.x);
        v.y = silu_f((v.y - mean) * rstd * gv.y + bv.y);
        v.z = silu_f((v.z - mean) * rstd * gv.z + bv.z);
        v.w = silu_f((v.w - mean) * rstd * gv.w + bv.w);
        *(float4*)(p + i) = v;
    }
}

// ------------------------- conv1: 3x64x64 -> 32x32x32 ----------------------
__global__ __launch_bounds__(256) void conv1_k(const float* __restrict__ in,
    const float* __restrict__ w, const float* __restrict__ bias, float* __restrict__ out)
{
    int n  = blockIdx.x;                 // chunk-local sample
    int yq = blockIdx.y;                 // 4 y-quarters
    int tx = threadIdx.x & 31;
    int ty = threadIdx.x >> 5;           // 0..7
    int y  = yq * 8 + ty;                // 0..31
    const float* ip = in + (size_t)n * 12288;

    float okf[16]; int offs[16];
#pragma unroll
    for (int ky = 0; ky < 4; ky++) {
        int yy = 2 * y - 1 + ky;
        bool yok = ((unsigned)yy < 64u);
#pragma unroll
        for (int kx = 0; kx < 4; kx++) {
            int xx = 2 * tx - 1 + kx;
            bool ok = yok && ((unsigned)xx < 64u);
            okf[ky*4+kx]  = ok ? 1.f : 0.f;
            offs[ky*4+kx] = ok ? yy * 64 + xx : 0;
        }
    }
    float iv[48];
#pragma unroll
    for (int c = 0; c < 3; c++)
#pragma unroll
        for (int q = 0; q < 16; q++)
            iv[c*16+q] = ip[c*4096 + offs[q]] * okf[q];

    float* op = out + (size_t)n * 32768 + y * 32 + tx;
#pragma unroll 4
    for (int oc = 0; oc < 32; oc++) {           // oc uniform -> weights s_load
        float acc = bias[oc];
        const float* wp = w + oc * 48;
#pragma unroll
        for (int q = 0; q < 48; q++) acc += iv[q] * wp[q];
        op[oc * 1024] = acc;
    }
}

// ------- conv2 + LN2 + SiLU: 32x32x32 -> 64x16x16 -------------------------
__global__ __launch_bounds__(256) void conv2_r(const float* __restrict__ in,
    const float* __restrict__ w, const float* __restrict__ bias,
    const float* __restrict__ lg, const float* __restrict__ lb,
    float* __restrict__ out)
{
    __shared__ __align__(16) float lds[8208];     // 4*1028 input + 4096 wt
    int n  = blockIdx.x;
    int tid = threadIdx.x;
    int wv  = tid >> 6;
    int g   = wv >> 1;                            // oc half 0/1
    int s   = ((wv & 1) << 6) | (tid & 63);       // 0..127
    int x   = s & 15, y0 = s >> 4;                // x 0..15, y0 0..7
    const float* ip = in + (size_t)n * 32768;

    int offs[2][16];
#pragma unroll
    for (int p = 0; p < 2; p++) {
        int y = y0 + 8 * p;
#pragma unroll
        for (int ky = 0; ky < 4; ky++) {
            int yi = 2 * y - 1 + ky;
#pragma unroll
            for (int kx = 0; kx < 4; kx++) {
                int xi = 2 * x - 1 + kx;
                bool ok = ((unsigned)yi < 32u) && ((unsigned)xi < 32u);
                int rot = ((xi >> 2) + (yi & 7)) & 7;
                int foff = yi * 32 + rot * 4 + (xi & 3);
                offs[p][ky*4+kx] = ok ? (4 + foff) * 4 : 0;   // bytes; 0 = zero slot
            }
        }
    }
    if (tid < 16) lds[(tid >> 2) * 1028 + (tid & 3)] = 0.f;   // zero slots

    float acc0[32], acc1[32];
#pragma unroll
    for (int i = 0; i < 32; i++) { float bv = bias[g*32 + i]; acc0[i] = bv; acc1[i] = bv; }

#pragma unroll 1
    for (int ch = 0; ch < 8; ch++) {              // 8 chunks x 4 channels
        __syncthreads();
        {   // stage input: 4 ch x 1024 fl, rotated rows
            const float4* gs = (const float4*)(ip + (ch << 12));
#pragma unroll
            for (int k = 0; k < 4; k++) {
                int gid = tid + (k << 8);         // 0..1023 f4s
                int cc = gid >> 8, r = (gid >> 3) & 31, s4 = gid & 7;
                int rs = (s4 + (r & 7)) & 7;
                *(float4*)&lds[cc*1028 + 4 + r*32 + rs*4] = gs[gid];
            }
            // stage weights: 4 ch x 64 oc x 16 (linear in tid)
            int oc = tid >> 2, i4 = tid & 3;
            const float* wg = w + (size_t)oc * 512 + (ch << 6) + i4 * 4;
#pragma unroll
            for (int cc = 0; cc < 4; cc++)
                *(float4*)&lds[4112 + cc*1024 + oc*16 + i4*4] =
                    *(const float4*)(wg + cc * 16);
        }
        __syncthreads();
#pragma unroll 1
        for (int cc = 0; cc < 4; cc++) {
            const char* cb = (const char*)lds + cc * 4112;
            float iv0[16], iv1[16];
#pragma unroll
            for (int q = 0; q < 16; q++) {
                iv0[q] = *(const float*)(cb + offs[0][q]);
                iv1[q] = *(const float*)(cb + offs[1][q]);
            }
            const float* wb = &lds[4112 + cc*1024 + g*512];   // wave-uniform base
#pragma unroll
            for (int o = 0; o < 32; o++) {
                float wt[16];
                *(float4*)&wt[0]  = *(const float4*)(wb + o*16);
                *(float4*)&wt[4]  = *(const float4*)(wb + o*16 + 4);
                *(float4*)&wt[8]  = *(const float4*)(wb + o*16 + 8);
                *(float4*)&wt[12] = *(const float4*)(wb + o*16 + 12);
#pragma unroll
                for (int q = 0; q < 16; q++) {
                    acc0[o] = fmaf(iv0[q], wt[q], acc0[o]);
                    acc1[o] = fmaf(iv1[q], wt[q], acc1[o]);
                }
            }
        }
    }
    // ---- fused LN2 + SiLU over the block-resident 16384 values ----
    float s1 = 0.f, s2 = 0.f;
#pragma unroll
    for (int o = 0; o < 32; o++) {
        s1 += acc0[o] + acc1[o];
        s2 += acc0[o]*acc0[o] + acc1[o]*acc1[o];
    }
    float mean, rstd;
    block_stats_256(s1, s2, 16384, mean, rstd);

    float* op = out + (size_t)n * 16384;
#pragma unroll
    for (int o = 0; o < 32; o++) {
        int f0 = (g*32 + o) * 256 + y0*16 + x;
        int f1 = (g*32 + o) * 256 + (y0+8)*16 + x;
        op[f0] = silu_f((acc0[o] - mean) * rstd * lg[f0] + lb[f0]);
        op[f1] = silu_f((acc1[o] - mean) * rstd * lg[f1] + lb[f1]);
    }
}

// ------- conv3 + LN3 + SiLU: 64x16x16 -> 128x8x8 ---------------------------
// R20: input rows at stride 20 (2-way bank max for stride-2 taps); per-row
// reads b32+b64+b32 over the consecutive taps 2x-1..2x+2; OOB -> zero slot
// by address select. Weights: R19 [oc][64] layout, linear staging,
// half-wave-uniform broadcast reads. 8 groups x 16 oc, 2 pos/thread.
__global__ __launch_bounds__(256) void conv3_r(const float* __restrict__ in,
    const float* __restrict__ w, const float* __restrict__ bias,
    const float* __restrict__ lg, const float* __restrict__ lb,
    float* __restrict__ out)
{
    __shared__ __align__(16) float lds[9488];    // 4*(4+16*20)=1296 in + 8192 wt
    int n   = blockIdx.x;
    int tid = threadIdx.x;
    int g   = tid >> 5;                  // 0..7 -> oc group (16 oc)
    int slot= tid & 31;
    int x   = slot & 7, y0 = slot >> 3;  // x 0..7, y0 0..3

    // per-row addresses (channel-relative floats): L (2x-1), M (2x,2x+1), R (2x+2)
    int aL[8], aM[8], aR[8];
#pragma unroll
    for (int p = 0; p < 2; p++) {
#pragma unroll
        for (int ky = 0; ky < 4; ky++) {
            int yi = 2 * (y0 + 4 * p) - 1 + ky;
            bool yok = ((unsigned)yi < 16u);
            int rb = 4 + yi * 20 + 2 * x;
            int i = p * 4 + ky;
            aM[i] = yok ? rb : 0;                    // zero slots 0,1 (even)
            aL[i] = (yok && x > 0) ? rb - 1 : 2;     // zero slot 2
            aR[i] = (yok && x < 7) ? rb + 2 : 3;     // zero slot 3
        }
    }
    if (tid < 16) lds[(tid >> 2) * 324 + (tid & 3)] = 0.f;    // zero slots

    float acc0[16], acc1[16];
#pragma unroll
    for (int i = 0; i < 16; i++) { float bv = bias[g*16 + i]; acc0[i] = bv; acc1[i] = bv; }

    const float* ip = in + (size_t)n * 16384;
#pragma unroll 1
    for (int ch = 0; ch < 16; ch++) {             // 16 chunks x 4 channels
        __syncthreads();
        {   // stage input: 4 ch x 256 fl into stride-20 rows (1 f4/thread)
            const float4* gs = (const float4*)(ip + (ch << 10));
            int cc = tid >> 6, j = tid & 63;
            int r = j >> 2, s4 = j & 3;
            *(float4*)&lds[cc*324 + 4 + r*20 + s4*4] = gs[tid];
            // stage weights: [oc][64] layout, LINEAR writes (8 f4/thread)
#pragma unroll
            for (int k = 0; k < 8; k++) {
                int F  = (tid + (k << 8)) << 2;   // 0,4,..,8188
                int oc = F >> 6, jw = F & 63;
                *(float4*)&lds[1296 + F] =
                    *(const float4*)(w + (size_t)oc * 1024 + (ch << 6) + jw);
            }
        }
        __syncthreads();
#pragma unroll 1
        for (int cc = 0; cc < 4; cc++) {
            const float* cb = &lds[cc * 324];
            float iv0[16], iv1[16];
#pragma unroll
            for (int ky = 0; ky < 4; ky++) {
                iv0[ky*4+0] = cb[aL[ky]];
                float2 m0 = *(const float2*)&cb[aM[ky]];
                iv0[ky*4+1] = m0.x; iv0[ky*4+2] = m0.y;
                iv0[ky*4+3] = cb[aR[ky]];
                iv1[ky*4+0] = cb[aL[4+ky]];
                float2 m1 = *(const float2*)&cb[aM[4+ky]];
                iv1[ky*4+1] = m1.x; iv1[ky*4+2] = m1.y;
                iv1[ky*4+3] = cb[aR[4+ky]];
            }
            // weights for oc = g*16+o at lds[1296 + oc*64 + cc*16 + q]
            const float* wb = &lds[1296 + (g*16)*64 + cc*16];  // half-wave uniform
#pragma unroll
            for (int o = 0; o < 16; o++) {
                float wt[16];
                *(float4*)&wt[0]  = *(const float4*)(wb + o*64);
                *(float4*)&wt[4]  = *(const float4*)(wb + o*64 + 4);
                *(float4*)&wt[8]  = *(const float4*)(wb + o*64 + 8);
                *(float4*)&wt[12] = *(const float4*)(wb + o*64 + 12);
#pragma unroll
                for (int q = 0; q < 16; q++) {
                    acc0[o] = fmaf(iv0[q], wt[q], acc0[o]);
                    acc1[o] = fmaf(iv1[q], wt[q], acc1[o]);
                }
            }
        }
    }
    // ---- fused LN3 + SiLU over the block-resident 8192 values ----
    float s1 = 0.f, s2 = 0.f;
#pragma unroll
    for (int o = 0; o < 16; o++) {
        s1 += acc0[o] + acc1[o];
        s2 += acc0[o]*acc0[o] + acc1[o]*acc1[o];
    }
    float mean, rstd;
    block_stats_256(s1, s2, 8192, mean, rstd);

    float* op = out + (size_t)n * 8192;
#pragma unroll
    for (int o = 0; o < 16; o++) {
        int f0 = (g*16 + o) * 64 + slot;
        int f1 = (g*16 + o) * 64 + slot + 32;
        op[f0] = silu_f((acc0[o] - mean) * rstd * lg[f0] + lb[f0]);
        op[f1] = silu_f((acc1[o] - mean) * rstd * lg[f1] + lb[f1]);
    }
}

// ----- c4wT[c][oc][q] = conv4_w[oc][c*16+q]  (coalesced per-channel rows) --
__global__ __launch_bounds__(256) void tr_c4_k(const float* __restrict__ w,
                                               float* __restrict__ wt)
{
    int gi = blockIdx.x * 256 + threadIdx.x;     // 0..524287
    int q  = gi & 15;
    int t  = gi >> 4;                            // c*256 + oc
    int oc = t & 255;
    int c  = t >> 8;
    wt[gi] = w[(size_t)oc * 2048 + c * 16 + q];
}

// ----------------- conv4 + LN4 + SiLU: 128x8x8 -> 256x4x4 ------------------
__global__ __launch_bounds__(256) void conv4_f(const float* __restrict__ in,
    const float* __restrict__ wT, const float* __restrict__ bias,
    const float* __restrict__ g, const float* __restrict__ bet, float* __restrict__ out)
{
    int n  = blockIdx.x;
    int oc = threadIdx.x;                 // 0..255
    const float* ip = in + (size_t)n * 8192;

    float acc[16];
#pragma unroll
    for (int s = 0; s < 16; s++) acc[s] = bias[oc];

#pragma unroll 2
    for (int c = 0; c < 128; c++) {
        const float* ic = ip + c * 64;     // uniform base -> s_load, CSE'd
        const float4* wp = (const float4*)(wT + ((size_t)c * 256 + oc) * 16);
        float wf[16];
        *(float4*)&wf[0]  = wp[0];         // coalesced: lane stride 64B
        *(float4*)&wf[4]  = wp[1];
        *(float4*)&wf[8]  = wp[2];
        *(float4*)&wf[12] = wp[3];
#pragma unroll
        for (int y = 0; y < 4; y++)
#pragma unroll
        for (int x = 0; x < 4; x++) {
            float a = acc[y * 4 + x];
#pragma unroll
            for (int ky = 0; ky < 4; ky++) {
                int yy = 2 * y - 1 + ky;
                if (yy < 0 || yy > 7) continue;      // folds at compile time
#pragma unroll
                for (int kx = 0; kx < 4; kx++) {
                    int xx = 2 * x - 1 + kx;
                    if (xx < 0 || xx > 7) continue;
                    a += wf[ky * 4 + kx] * ic[yy * 8 + xx];
                }
            }
            acc[y * 4 + x] = a;
        }
    }
    float s = 0.f, s2 = 0.f;
#pragma unroll
    for (int q = 0; q < 16; q++) { s += acc[q]; s2 += acc[q] * acc[q]; }
    float mean, rstd;
    block_stats_256(s, s2, 4096, mean, rstd);

    float* op = out + (size_t)n * 4096;
#pragma unroll
    for (int q = 0; q < 16; q++) {
        int flat = oc * 16 + q;
        float v = (acc[q] - mean) * rstd * g[flat] + bet[flat];
        op[flat] = silu_f(v);
    }
}

// -------- transpose fc_w [256][4096] -> fcwT [4096][256] (LDS-tiled) -------
__global__ __launch_bounds__(256) void trfc_k(const float* __restrict__ w,
                                              float* __restrict__ wt)
{
    __shared__ float t[32][33];
    int bk = blockIdx.x * 32;             // k dim (4096)
    int bj = blockIdx.y * 32;             // j dim (256)
    int lx = threadIdx.x & 31, ly = threadIdx.x >> 5;   // 32 x 8
#pragma unroll
    for (int s = 0; s < 4; s++)
        t[ly + 8*s][lx] = w[(size_t)(bj + ly + 8*s) * 4096 + bk + lx];
    __syncthreads();
#pragma unroll
    for (int s = 0; s < 4; s++)
        wt[(size_t)(bk + ly + 8*s) * 256 + bj + lx] = t[lx][ly + 8*s];
}

// ---------------- fc: [S,4096] @ wT[4096][256], coalesced ------------------
__global__ __launch_bounds__(256) void fc_k2(const float* __restrict__ a,
    const float* __restrict__ wT, const float* __restrict__ bias, float* __restrict__ o)
{
    int n0 = blockIdx.x * 8;              // chunk-local rows
    int j  = threadIdx.x;
    float acc[8];
#pragma unroll
    for (int r = 0; r < 8; r++) acc[r] = 0.f;
    for (int k = 0; k < 4096; k += 4) {
        float wv0 = wT[(size_t)k * 256 + j];
        float wv1 = wT[(size_t)(k+1) * 256 + j];
        float wv2 = wT[(size_t)(k+2) * 256 + j];
        float wv3 = wT[(size_t)(k+3) * 256 + j];
#pragma unroll
        for (int r = 0; r < 8; r++) {
            const float* ar = a + (size_t)(n0 + r) * 4096 + k;   // uniform -> s_load x4
            acc[r] += wv0*ar[0] + wv1*ar[1] + wv2*ar[2] + wv3*ar[3];
        }
    }
    float bj = bias[j];
#pragma unroll
    for (int r = 0; r < 8; r++) o[(size_t)(n0 + r) * 256 + j] = acc[r] + bj;
}

// ----------- Fpost[n,j] = post_b[j] + feats[n,:] @ post_w[j,128:384] -------
__global__ __launch_bounds__(256) void fpost_k(const float* __restrict__ f,
    const float* __restrict__ w, const float* __restrict__ bias, float* __restrict__ o)
{
    int n0 = blockIdx.x * 4;
    int tid = threadIdx.x;
    float acc[4][4];
#pragma unroll
    for (int r = 0; r < 4; r++)
#pragma unroll
        for (int jj = 0; jj < 4; jj++) acc[r][jj] = 0.f;
    for (int k = 0; k < 256; k += 4) {
        float4 wv[4];
#pragma unroll
        for (int jj = 0; jj < 4; jj++)
            wv[jj] = *(const float4*)(w + (size_t)(tid + jj * 256) * 384 + 128 + k);
#pragma unroll
        for (int r = 0; r < 4; r++) {
            const float* fr = f + (size_t)(n0 + r) * 256 + k;    // uniform
            float a0 = fr[0], a1 = fr[1], a2 = fr[2], a3 = fr[3];
#pragma unroll
            for (int jj = 0; jj < 4; jj++)
                acc[r][jj] += wv[jj].x*a0 + wv[jj].y*a1 + wv[jj].z*a2 + wv[jj].w*a3;
        }
    }
#pragma unroll
    for (int jj = 0; jj < 4; jj++) {
        float bj = bias[tid + jj * 256];
#pragma unroll
        for (int r = 0; r < 4; r++)
            o[(size_t)(n0 + r) * 1024 + tid + jj * 256] = acc[r][jj] + bj;
    }
}

// ----------- prior[n,j] = prior_b[j] + h[n,:] @ prior_w[j,:] ---------------
__global__ __launch_bounds__(256) void prior_k(const float* __restrict__ h,
    const float* __restrict__ w, const float* __restrict__ bias, float* __restrict__ o)
{
    int n0 = blockIdx.x * 4;
    int tid = threadIdx.x;
    float acc[4][4];
#pragma unroll
    for (int r = 0; r < 4; r++)
#pragma unroll
        for (int jj = 0; jj < 4; jj++) acc[r][jj] = 0.f;
    for (int k = 0; k < 128; k += 4) {
        float4 wv[4];
#pragma unroll
        for (int jj = 0; jj < 4; jj++)
            wv[jj] = *(const float4*)(w + (size_t)(tid + jj * 256) * 128 + k);
#pragma unroll
        for (int r = 0; r < 4; r++) {
            const float* hr = h + (size_t)(n0 + r) * 128 + k;    // uniform
            float a0 = hr[0], a1 = hr[1], a2 = hr[2], a3 = hr[3];
#pragma unroll
            for (int jj = 0; jj < 4; jj++)
                acc[r][jj] += wv[jj].x*a0 + wv[jj].y*a1 + wv[jj].z*a2 + wv[jj].w*a3;
        }
    }
#pragma unroll
    for (int jj = 0; jj < 4; jj++) {
        float bj = bias[tid + jj * 256];
#pragma unroll
        for (int r = 0; r < 4; r++)
            o[(size_t)(n0 + r) * 1024 + tid + jj * 256] = acc[r][jj] + bj;
    }
}

// ----------- Ai[n,j] = bih[j] + actions[n,:] @ wih[j,1024:1030] ------------
__global__ __launch_bounds__(128) void ai_k(const float* __restrict__ act,
    const float* __restrict__ wih, const float* __restrict__ bih, float* __restrict__ o)
{
    int n = blockIdx.x;
    int j = blockIdx.y * 128 + threadIdx.x;     // 0..383
    const float* ar = act + (size_t)n * 6;       // uniform
    const float* wr = wih + (size_t)j * 1030 + 1024;
    float acc = bih[j];
#pragma unroll
    for (int k = 0; k < 6; k++) acc += ar[k] * wr[k];
    o[(size_t)n * 384 + j] = acc;
}

// ----------- wihT[k,j] = wih[j,k]  (z-part only, k<1024) -------------------
__global__ __launch_bounds__(256) void tr_k(const float* __restrict__ wih,
                                            float* __restrict__ wt)
{
    int g = blockIdx.x * 256 + threadIdx.x;      // 0..393215
    int k = g / 384;
    int j = g - k * 384;
    wt[g] = wih[(size_t)j * 1030 + k];
}

// ----- whhV[k4][j][c] = whh[j][4*k4+c]  (float4-packed, coalesced) ---------
__global__ __launch_bounds__(256) void tr_whh_k(const float* __restrict__ whh,
                                                float* __restrict__ wt)
{
    int g = blockIdx.x * 256 + threadIdx.x;      // 0..49151
    int c  = g & 3;
    int jk = g >> 2;                             // 0..12287
    int j  = jk % 384;
    int k4 = jk / 384;                           // 0..31
    wt[g] = whh[(size_t)j * 128 + k4 * 4 + c];
}

// ----- pwV[k4][j][c] = post_w[j][4*k4+c] (h-cols only, float4-packed) ------
__global__ __launch_bounds__(256) void tr_pw_k(const float* __restrict__ pw,
                                               float* __restrict__ wt)
{
    int g = blockIdx.x * 256 + threadIdx.x;      // 0..131071
    int c  = g & 3;
    int jk = g >> 2;                             // 0..32767
    int j  = jk & 1023;
    int k4 = jk >> 10;                           // 0..31
    wt[g] = pw[(size_t)j * 384 + k4 * 4 + c];
}

// ------------------- GRU recurrence (1 block / sample, 32 steps) -----------
__global__ __launch_bounds__(1024) void gru_k(const float* __restrict__ wihT,
    const float* __restrict__ whhV, const float* __restrict__ bhh,
    const float* __restrict__ ai, const float* __restrict__ fpost,
    const float* __restrict__ pwV, float* __restrict__ out,
    float* __restrict__ hs, float* __restrict__ ghs, int* __restrict__ idxs,
    int t0)
{
    float* out_post = out + 1048576;
    float* out_h    = out + 2097152;
    float* out_z    = out + 2228224;
    int b   = blockIdx.x;
    int tid = threadIdx.x;
    __shared__ __align__(16) float h[128];
    __shared__ float gi[384], gh[384];
    __shared__ int idx[32];
    if (t0 == 0) {
        if (tid < 128) h[tid] = 0.f;
        if (tid >= 512 && tid < 896) gh[tid - 512] = bhh[tid - 512]; // gh(0)
    } else {
        if (tid < 128) h[tid] = hs[b * 128 + tid];
        if (tid >= 512 && tid < 896) gh[tid - 512] = ghs[b * 384 + tid - 512];
        if (tid < 32) idx[tid] = idxs[b * 32 + tid];
    }
    __syncthreads();

    const float4* h4  = (const float4*)h;
    const float4* wv4 = (const float4*)whhV;
    const float4* pv4 = (const float4*)pwV;

    for (int tt = 0; tt < 32; tt++) {
        int t = t0 + tt;
        int n = b * 64 + t;
        // ---- P1: gi(t) = ai(t) + one-hot gather over idx(t-1) ----
        if (tid < 384) {
            float a = ai[(size_t)n * 384 + tid];
            if (t > 0) {
#pragma unroll 8
                for (int c = 0; c < 32; c++)
                    a += wihT[(size_t)(c * 32 + idx[c]) * 384 + tid];
            }
            gi[tid] = a;
        }
        __syncthreads();                                    // B1
        // ---- P2: h(t) from gi(t), gh(t) ----
        if (tid < 128) {
            float r  = sigm_f(gi[tid] + gh[tid]);
            float u  = sigm_f(gi[128 + tid] + gh[128 + tid]);
            float nn = tanhf(gi[256 + tid] + r * gh[256 + tid]);
            float hn = (1.f - u) * nn + u * h[tid];
            h[tid] = hn;
            out_h[(size_t)n * 128 + tid] = hn;
        }
        __syncthreads();                                    // B2
        // ---- P3a: post(t) + argmax -> idx(t)   [tid < 512]
        // ---- P3b: gh(t+1) = bhh + whhV.h(t)    [512 <= tid < 896]
        if (tid < 512) {
            float a0 = fpost[(size_t)n * 1024 + tid];
            float a1 = fpost[(size_t)n * 1024 + 512 + tid];
#pragma unroll 16
            for (int k4 = 0; k4 < 32; k4++) {
                float4 hq = h4[k4];                  // broadcast, reused x2
                float4 w0 = pv4[k4 * 1024 + tid];
                float4 w1 = pv4[k4 * 1024 + 512 + tid];
                a0 += w0.x*hq.x + w0.y*hq.y + w0.z*hq.z + w0.w*hq.w;
                a1 += w1.x*hq.x + w1.y*hq.y + w1.z*hq.z + w1.w*hq.w;
            }
            out_post[(size_t)n * 1024 + tid]       = a0;
            out_post[(size_t)n * 1024 + 512 + tid] = a1;

            // first-max argmax over each 32-lane chunk, in-register butterfly
            float b0 = a0, b1 = a1;
            int i0 = tid & 31, i1 = tid & 31;
#pragma unroll
            for (int m = 16; m >= 1; m >>= 1) {
                float ob0 = __shfl_xor(b0, m);
                int   oi0 = __shfl_xor(i0, m);
                float ob1 = __shfl_xor(b1, m);
                int   oi1 = __shfl_xor(i1, m);
                if (ob0 > b0 || (ob0 == b0 && oi0 < i0)) { b0 = ob0; i0 = oi0; }
                if (ob1 > b1 || (ob1 == b1 && oi1 < i1)) { b1 = ob1; i1 = oi1; }
            }
            out_z[(size_t)n * 1024 + tid]       = ((tid & 31) == i0) ? 1.f : 0.f;
            out_z[(size_t)n * 1024 + 512 + tid] = ((tid & 31) == i1) ? 1.f : 0.f;
            if ((tid & 31) == 0) {
                idx[tid >> 5]        = i0;
                idx[(tid >> 5) + 16] = i1;
            }
        } else if (tid < 896) {
            int r = tid - 512;                       // 0..383
            float a2 = bhh[r];
#pragma unroll 8
            for (int k4 = 0; k4 < 32; k4++) {
                float4 wq = wv4[k4 * 384 + r];       // coalesced 16B/lane
                float4 hq = h4[k4];                  // broadcast b128
                a2 += wq.x*hq.x + wq.y*hq.y + wq.z*hq.z + wq.w*hq.w;
            }
            gh[r] = a2;
        }
        __syncthreads();                                    // B3
    }
    // ---- persist state for next 32-step launch ----
    if (t0 == 0) {
        if (tid < 128) hs[b * 128 + tid] = h[tid];
        else if (tid >= 512 && tid < 896) ghs[b * 384 + tid - 512] = gh[tid - 512];
        if (tid < 32) idxs[b * 32 + tid] = idx[tid];
    }
}

// ---------------------------------------------------------------------------
extern "C" void kernel_launch(void* const* d_in, const int* in_sizes, int n_in,
                              void* d_out, int out_size, void* d_ws, size_t ws_size,
                              hipStream_t stream)
{
    const float* states  = (const float*)d_in[0];
    const float* actions = (const float*)d_in[1];
    const float* c1w = (const float*)d_in[2];  const float* c1b = (const float*)d_in[3];
    const float* l1g = (const float*)d_in[4];  const float* l1b = (const float*)d_in[5];
    const float* c2w = (const float*)d_in[6];  const float* c2b = (const float*)d_in[7];
    const float* l2g = (const float*)d_in[8];  const float* l2b = (const float*)d_in[9];
    const float* c3w = (const float*)d_in[10]; const float* c3b = (const float*)d_in[11];
    const float* l3g = (const float*)d_in[12]; const float* l3b = (const float*)d_in[13];
    const float* c4w = (const float*)d_in[14]; const float* c4b = (const float*)d_in[15];
    const float* l4g = (const float*)d_in[16]; const float* l4b = (const float*)d_in[17];
    const float* fcw = (const float*)d_in[18]; const float* fcb = (const float*)d_in[19];
    const float* wih = (const float*)d_in[20]; const float* whh = (const float*)d_in[21];
    const float* bih = (const float*)d_in[22]; const float* bhh = (const float*)d_in[23];
    const float* prw = (const float*)d_in[24]; const float* prb = (const float*)d_in[25];
    const float* pw  = (const float*)d_in[26]; const float* pb  = (const float*)d_in[27];

    float* out = (float*)d_out;
    float* ws  = (float*)d_ws;

    // ---- adaptive chunking: largest S whose footprint fits ws_size --------
    // footprint = (S*49152 + fixed 3,859,968) floats
    size_t S = 64;
    {
        const size_t cands[4] = {1024, 512, 256, 128};
        for (int i = 0; i < 4; i++) {
            size_t need = (cands[i] * 49152ull + 3859968ull) * 4ull;
            if (need <= ws_size) { S = cands[i]; break; }
        }
    }
    int C = (int)(1024 / S);

    float* bufA  = ws;                       // S*32768
    float* bufB  = bufA + S * 32768;         // S*16384
    float* feats = bufB + S * 16384;         //   262,144
    float* fpost = feats + 262144;           // 1,048,576
    float* aibuf = fpost + 1048576;          //   393,216
    float* wihT  = aibuf + 393216;           //   393,216
    float* fcwT  = wihT + 393216;            // 1,048,576
    float* whhV  = fcwT + 1048576;           //    49,152
    float* pwV   = whhV + 49152;             //   131,072
    float* c4wT  = pwV + 131072;             //   524,288
    float* hs    = c4wT + 524288;            //     2,048
    float* ghs   = hs + 2048;                //     6,144
    int*   idxs  = (int*)(ghs + 6144);       //       512 ints

    trfc_k<<<dim3(128, 8), 256, 0, stream>>>(fcw, fcwT);
    tr_whh_k<<<192, 256, 0, stream>>>(whh, whhV);
    tr_pw_k<<<512, 256, 0, stream>>>(pw, pwV);
    tr_c4_k<<<2048, 256, 0, stream>>>(c4w, c4wT);

    for (int cc = 0; cc < C; cc++) {
        size_t n0 = (size_t)cc * S;
        conv1_k<<<dim3((unsigned)S, 4), 256, 0, stream>>>(states + n0 * 12288, c1w, c1b, bufA);
        ln_fuse_k<<<(unsigned)S, 256, 0, stream>>>(bufA, l1g, l1b, 32768);
        conv2_r<<<(unsigned)S, 256, 0, stream>>>(bufA, c2w, c2b, l2g, l2b, bufB);
        conv3_r<<<(unsigned)S, 256, 0, stream>>>(bufB, c3w, c3b, l3g, l3b, bufA);
        conv4_f<<<(unsigned)S, 256, 0, stream>>>(bufA, c4wT, c4b, l4g, l4b, bufB);
        fc_k2<<<(unsigned)(S / 8), 256, 0, stream>>>(bufB, fcwT, fcb, feats + n0 * 256);
    }

    fpost_k<<<256, 256, 0, stream>>>(feats, pw, pb, fpost);
    ai_k<<<dim3(1024, 3), 128, 0, stream>>>(actions, wih, bih, aibuf);
    tr_k<<<1536, 256, 0, stream>>>(wih, wihT);

    for (int t0 = 0; t0 < 64; t0 += 32)
        gru_k<<<16, 1024, 0, stream>>>(wihT, whhV, bhh, aibuf, fpost, pwV, out,
                                       hs, ghs, idxs, t0);
    prior_k<<<256, 256, 0, stream>>>(out + 2097152, prw, prb, out);
}